// Round 14
// baseline (148.092 us; speedup 1.0000x reference)
//
#include <hip/hip_runtime.h>

// 22-qubit, 3-layer RY variational circuit — forward-frame 2-sweep version.
// Real/imag planes evolve independently (all gates real).
//
// Forward frame: state kept in natural position order; CNOT chains folded into
// rotation masks/signs. sigma(x) = x ^ (x<<1).
//   L0 q: mask e_q,                sign = p_q
//   L1 q: mask e_q^e_{q+1},        sign = parity(p_0..p_q)
//   L2 q: mask e_q^e_{q+2},        sign = parity(p_q, p_{q-2}, ...)
//   output: out[l] = buf[sigma^2(l)]  (kfinal gather)
//
// R14: split bit 13->12 (sweep1 masks bits<=12: 36 gates, 2^13 tile, 32KB LDS,
// 256 thr; sweep2 masks bits 11..21: 30 gates, 2048h x 4lo, 32KB LDS).
// 5 blocks/CU (160KB LDS exactly) => ~20 waves/CU vs R13's ~8-16.
// All schedule reorderings re-verified via f1(m2)==f2(m1) mod 2.
// W intermediates f32; tmp planes bf16. Fallback: proven R6 tier-C.

#define NQ 22
#define NSTATES (1u << NQ)
#define IDXMASK (NSTATES - 1u)

__device__ __forceinline__ unsigned short f2bf(float x) {
  unsigned int b = __float_as_uint(x);
  b += 0x7FFFu + ((b >> 16) & 1u);   // round-to-nearest-even
  return (unsigned short)(b >> 16);
}
__device__ __forceinline__ float bf2f(unsigned short h) {
  return __uint_as_float((unsigned int)h << 16);
}
// LDS swizzle for 13-bit local index: bank bits 0..4 ^= l5..9 ^ l10..12.
__device__ __forceinline__ unsigned SW(unsigned l) {
  return l ^ ((l >> 5) & 31u) ^ ((l >> 10) & 7u);
}

// Generalized RY butterfly. Pairs differ by lane-mask ML (shfl) / reg-mask MR.
// SM = sign-functional support (p-bits); RS = shift of reg idx into p-bits.
// Pair enumeration by LOWEST set bit of MR (handles multi-bit masks).
template <int ML, int MR, int RS, unsigned SM>
__device__ __forceinline__ void rot(float (&v)[32], float c, float s, unsigned pbase) {
  int sb = __popc(pbase & SM) & 1;
  float sp = sb ? s : -s;
  constexpr int LB = MR & (-MR);
  if (ML == 0) {
#pragma unroll
    for (int i = 0; i < 32; ++i)
      if (!(i & LB)) {
        const int j = i ^ MR;
        const int pi = __builtin_popcount(((unsigned)i << RS) & SM) & 1;
        const int pj = __builtin_popcount(((unsigned)j << RS) & SM) & 1;
        float a = v[i], b = v[j];
        v[i] = fmaf(pi ? -sp : sp, b, c * a);
        v[j] = fmaf(pj ? -sp : sp, a, c * b);
      }
  } else if (MR == 0) {
#pragma unroll
    for (int i = 0; i < 32; ++i) {
      float o = __shfl_xor(v[i], ML, 64);
      const int pi = __builtin_popcount(((unsigned)i << RS) & SM) & 1;
      v[i] = fmaf(pi ? -sp : sp, o, c * v[i]);
    }
  } else {
#pragma unroll
    for (int i = 0; i < 32; ++i)
      if (!(i & LB)) {
        const int j = i ^ MR;
        float oa = __shfl_xor(v[j], ML, 64);
        float ob = __shfl_xor(v[i], ML, 64);
        const int pi = __builtin_popcount(((unsigned)i << RS) & SM) & 1;
        const int pj = __builtin_popcount(((unsigned)j << RS) & SM) & 1;
        v[i] = fmaf(pi ? -sp : sp, oa, c * v[i]);
        v[j] = fmaf(pj ? -sp : sp, ob, c * v[j]);
      }
  }
}

// setup: input dtype flag + 66 sincos pairs
__global__ void ksetup(const unsigned int* __restrict__ probe,
                       const void* __restrict__ prm,
                       float* __restrict__ csb, int* __restrict__ flagp) {
  __shared__ int anybad;
  if (threadIdx.x == 0) anybad = 0;
  __syncthreads();
  int bad = 0;
  for (int i = threadIdx.x; i < 4096; i += 256) {
    unsigned e = (probe[i] >> 7) & 0xFFu;
    bad |= (e >= 0x90u);
  }
  if (bad) anybad = 1;
  __syncthreads();
  int f = anybad ? 0 : 1;
  if (threadIdx.x == 0) *flagp = f;
  int i = threadIdx.x;
  if (i < 66) {
    float a = f ? bf2f(((const unsigned short*)prm)[i]) : ((const float*)prm)[i];
    float sv, cv;
    sincosf(0.5f * a, &sv, &cv);
    csb[i] = cv; csb[66 + i] = sv;
  }
}

#define RC(k) csb[k], csb[66 + (k)]

// ---- sweep 1: masks within bits 0..12 (36 gates) ----
// tile = 2^13 f32 (32KB LDS), 256 threads, 32 elems/thread, 5 blocks/CU.
// A/C layout: regs=l8..12, lane=l2..7, wv=l0..1
// B layout:   regs=l0..4,  lane=l5..10, wv=l11..12
__global__ void __launch_bounds__(256, 5)
ksweep1(const void* re, const void* im, float* __restrict__ Wr,
        float* __restrict__ Wi, const float* __restrict__ csb,
        const int* __restrict__ flag) {
  __shared__ float ld[8192];
  int tid = threadIdx.x;
  int f = *flag;
  int pl = blockIdx.y;
  const void* src = (pl ^ (f ? 0 : 1)) ? im : re;
  float* W = pl ? Wi : Wr;
  unsigned tb = (unsigned)blockIdx.x << 13;

  if (f) {
    const unsigned short* sp = (const unsigned short*)src + tb;
#pragma unroll
    for (int k = 0; k < 4; ++k) {
      unsigned C = (unsigned)k * 256 + tid;       // 16B chunk = 8 bf16
      uint4 q = *reinterpret_cast<const uint4*>(sp + C * 8);
      unsigned e0 = C * 8;
      ld[SW(e0 + 0)] = bf2f((unsigned short)(q.x & 0xFFFFu));
      ld[SW(e0 + 1)] = bf2f((unsigned short)(q.x >> 16));
      ld[SW(e0 + 2)] = bf2f((unsigned short)(q.y & 0xFFFFu));
      ld[SW(e0 + 3)] = bf2f((unsigned short)(q.y >> 16));
      ld[SW(e0 + 4)] = bf2f((unsigned short)(q.z & 0xFFFFu));
      ld[SW(e0 + 5)] = bf2f((unsigned short)(q.z >> 16));
      ld[SW(e0 + 6)] = bf2f((unsigned short)(q.w & 0xFFFFu));
      ld[SW(e0 + 7)] = bf2f((unsigned short)(q.w >> 16));
    }
  } else {
    const float* sp = (const float*)src + tb;
#pragma unroll
    for (int k = 0; k < 8; ++k) {
      unsigned C = (unsigned)k * 256 + tid;       // 16B chunk = 4 f32
      float4 t = *reinterpret_cast<const float4*>(sp + C * 4);
      unsigned e0 = C * 4;
      ld[SW(e0 + 0)] = t.x; ld[SW(e0 + 1)] = t.y;
      ld[SW(e0 + 2)] = t.z; ld[SW(e0 + 3)] = t.w;
    }
  }
  __syncthreads();

  int lane = tid & 63, wv = tid >> 6;              // wv 0..3
  unsigned lbA = (unsigned)wv | ((unsigned)lane << 2);
  unsigned pbA = tb | lbA;
  float v[32];

  // ---- phase A: L0 q2..12 ----
#pragma unroll
  for (int i = 0; i < 32; ++i) v[i] = ld[SW(lbA | ((unsigned)i << 8))];
  rot<1, 0, 8, (1u << 2)>(v, RC(2), pbA);
  rot<2, 0, 8, (1u << 3)>(v, RC(3), pbA);
  rot<4, 0, 8, (1u << 4)>(v, RC(4), pbA);
  rot<8, 0, 8, (1u << 5)>(v, RC(5), pbA);
  rot<16, 0, 8, (1u << 6)>(v, RC(6), pbA);
  rot<32, 0, 8, (1u << 7)>(v, RC(7), pbA);
  rot<0, 1, 8, (1u << 8)>(v, RC(8), pbA);
  rot<0, 2, 8, (1u << 9)>(v, RC(9), pbA);
  rot<0, 4, 8, (1u << 10)>(v, RC(10), pbA);
  rot<0, 8, 8, (1u << 11)>(v, RC(11), pbA);
  rot<0, 16, 8, (1u << 12)>(v, RC(12), pbA);
#pragma unroll
  for (int i = 0; i < 32; ++i) ld[SW(lbA | ((unsigned)i << 8))] = v[i];
  __syncthreads();

  // ---- phase B: L0 q0,1; L1 q0..9; L2 q0..8 ----
  unsigned lbB = ((unsigned)lane << 5) | ((unsigned)wv << 11);
  unsigned pbB = tb | lbB;
#pragma unroll
  for (int i = 0; i < 32; ++i) v[i] = ld[SW(lbB | (unsigned)i)];
  rot<0, 1, 0, 0x1u>(v, RC(0), pbB);
  rot<0, 2, 0, 0x2u>(v, RC(1), pbB);
  rot<0, 3, 0, 0x1u>(v, RC(22), pbB);
  rot<0, 6, 0, 0x3u>(v, RC(23), pbB);
  rot<0, 12, 0, 0x7u>(v, RC(24), pbB);
  rot<0, 24, 0, 0xFu>(v, RC(25), pbB);
  rot<1, 16, 0, 0x1Fu>(v, RC(26), pbB);
  rot<3, 0, 0, 0x3Fu>(v, RC(27), pbB);
  rot<6, 0, 0, 0x7Fu>(v, RC(28), pbB);
  rot<12, 0, 0, 0xFFu>(v, RC(29), pbB);
  rot<24, 0, 0, 0x1FFu>(v, RC(30), pbB);
  rot<48, 0, 0, 0x3FFu>(v, RC(31), pbB);
  rot<0, 5, 0, 0x1u>(v, RC(44), pbB);
  rot<0, 10, 0, 0x2u>(v, RC(45), pbB);
  rot<0, 20, 0, 0x5u>(v, RC(46), pbB);
  rot<1, 8, 0, 0xAu>(v, RC(47), pbB);
  rot<2, 16, 0, 0x15u>(v, RC(48), pbB);
  rot<5, 0, 0, 0x2Au>(v, RC(49), pbB);
  rot<10, 0, 0, 0x55u>(v, RC(50), pbB);
  rot<20, 0, 0, 0xAAu>(v, RC(51), pbB);
  rot<40, 0, 0, 0x155u>(v, RC(52), pbB);
#pragma unroll
  for (int i = 0; i < 32; ++i) ld[SW(lbB | (unsigned)i)] = v[i];
  __syncthreads();

  // ---- phase C (= A layout): L1 q10,11; L2 q9,10 ----
#pragma unroll
  for (int i = 0; i < 32; ++i) v[i] = ld[SW(lbA | ((unsigned)i << 8))];
  rot<0, 12, 8, 0x7FFu>(v, RC(32), pbA);
  rot<0, 24, 8, 0xFFFu>(v, RC(33), pbA);
  rot<0, 10, 8, 0x2AAu>(v, RC(53), pbA);
  rot<0, 20, 8, 0x555u>(v, RC(54), pbA);
#pragma unroll
  for (int i = 0; i < 32; ++i) ld[SW(lbA | ((unsigned)i << 8))] = v[i];
  __syncthreads();

  // store f32 contiguous
#pragma unroll
  for (int k = 0; k < 8; ++k) {
    unsigned C = (unsigned)k * 256 + tid;
    unsigned e0 = C * 4;
    float4 t;
    t.x = ld[SW(e0 + 0)]; t.y = ld[SW(e0 + 1)];
    t.z = ld[SW(e0 + 2)]; t.w = ld[SW(e0 + 3)];
    *reinterpret_cast<float4*>(W + tb + e0) = t;
  }
}

// ---- sweep 2: masks within bits 11..21 (30 gates), single phase ----
// tile = 2048 h (p11..21) x 4 lo (p0..1) = 2^13 f32 (32KB); cb = p2..10.
// layout D: regs=l8..12 (p17..21), lane=l2..7 (p11..16), wv=l0..1 (p0..1).
// Per-plane blocks (grid.y); writes bf16 plane to tmp (p-order).
__global__ void __launch_bounds__(256, 5)
ksweep2(const float* __restrict__ Wr, const float* __restrict__ Wi,
        unsigned short* __restrict__ tR, unsigned short* __restrict__ tI,
        const float* __restrict__ csb) {
  __shared__ float ld[8192];
  int tid = threadIdx.x;
  int pl = blockIdx.y;
  const float* W = pl ? Wi : Wr;
  unsigned short* T = pl ? tI : tR;
  unsigned cb = blockIdx.x;             // p2..10

  // stage: chunk h = k*256+tid, 4 f32 (p0..1)
#pragma unroll
  for (int k = 0; k < 8; ++k) {
    unsigned h = (unsigned)k * 256 + tid;
    float4 t = *reinterpret_cast<const float4*>(
        W + ((size_t)h << 11) + ((size_t)cb << 2));
    unsigned e0 = h << 2;
    ld[SW(e0 + 0)] = t.x; ld[SW(e0 + 1)] = t.y;
    ld[SW(e0 + 2)] = t.z; ld[SW(e0 + 3)] = t.w;
  }
  __syncthreads();

  int lane = tid & 63, wv = tid >> 6;   // wv 0..3
  unsigned lbD = (unsigned)wv | ((unsigned)lane << 2);
  unsigned pbD = (unsigned)wv | (cb << 2) | ((unsigned)lane << 11);
  float v[32];
#pragma unroll
  for (int i = 0; i < 32; ++i) v[i] = ld[SW(lbD | ((unsigned)i << 8))];
  // L0 q13..21
  rot<4, 0, 17, (1u << 13)>(v, RC(13), pbD);
  rot<8, 0, 17, (1u << 14)>(v, RC(14), pbD);
  rot<16, 0, 17, (1u << 15)>(v, RC(15), pbD);
  rot<32, 0, 17, (1u << 16)>(v, RC(16), pbD);
  rot<0, 1, 17, (1u << 17)>(v, RC(17), pbD);
  rot<0, 2, 17, (1u << 18)>(v, RC(18), pbD);
  rot<0, 4, 17, (1u << 19)>(v, RC(19), pbD);
  rot<0, 8, 17, (1u << 20)>(v, RC(20), pbD);
  rot<0, 16, 17, (1u << 21)>(v, RC(21), pbD);
  // L1 q12..21
  rot<6, 0, 17, 0x1FFFu>(v, RC(34), pbD);
  rot<12, 0, 17, 0x3FFFu>(v, RC(35), pbD);
  rot<24, 0, 17, 0x7FFFu>(v, RC(36), pbD);
  rot<48, 0, 17, 0xFFFFu>(v, RC(37), pbD);
  rot<32, 1, 17, 0x1FFFFu>(v, RC(38), pbD);
  rot<0, 3, 17, 0x3FFFFu>(v, RC(39), pbD);
  rot<0, 6, 17, 0x7FFFFu>(v, RC(40), pbD);
  rot<0, 12, 17, 0xFFFFFu>(v, RC(41), pbD);
  rot<0, 24, 17, 0x1FFFFFu>(v, RC(42), pbD);
  rot<0, 16, 17, 0x3FFFFFu>(v, RC(43), pbD);
  // L2 q11..21
  rot<5, 0, 17, 0xAAAu>(v, RC(55), pbD);
  rot<10, 0, 17, 0x1555u>(v, RC(56), pbD);
  rot<20, 0, 17, 0x2AAAu>(v, RC(57), pbD);
  rot<40, 0, 17, 0x5555u>(v, RC(58), pbD);
  rot<16, 1, 17, 0xAAAAu>(v, RC(59), pbD);
  rot<32, 2, 17, 0x15555u>(v, RC(60), pbD);
  rot<0, 5, 17, 0x2AAAAu>(v, RC(61), pbD);
  rot<0, 10, 17, 0x55555u>(v, RC(62), pbD);
  rot<0, 20, 17, 0xAAAAAu>(v, RC(63), pbD);
  rot<0, 8, 17, 0x155555u>(v, RC(64), pbD);
  rot<0, 16, 17, 0x2AAAAAu>(v, RC(65), pbD);
#pragma unroll
  for (int i = 0; i < 32; ++i) ld[SW(lbD | ((unsigned)i << 8))] = v[i];
  __syncthreads();

  // pack out: bf16 plane, p-order, 8B ushort4 stores
#pragma unroll
  for (int k = 0; k < 8; ++k) {
    unsigned h = (unsigned)k * 256 + tid;
    unsigned e0 = h << 2;
    ushort4 o = make_ushort4(f2bf(ld[SW(e0 + 0)]), f2bf(ld[SW(e0 + 1)]),
                             f2bf(ld[SW(e0 + 2)]), f2bf(ld[SW(e0 + 3)]));
    *reinterpret_cast<ushort4*>(T + ((size_t)h << 11) + ((size_t)cb << 2)) = o;
  }
}

// ---- final gather + pack: out32[l] = tR[s2(l)] | tI[s2(l)]<<16 ----
// s2(l^e) = s2(l) ^ {0,5,10,15}[e]; all 4 targets in one 16-ushort window.
__global__ void __launch_bounds__(256)
kfinal(const unsigned short* __restrict__ tR,
       const unsigned short* __restrict__ tI, unsigned* __restrict__ out32) {
  unsigned t = blockIdx.x * 256 + threadIdx.x;   // quad id [0, 2^20)
  unsigned lb = t << 2;
  unsigned s = (lb ^ (lb << 2)) & IDXMASK;       // sigma^2(lb), %4 == 0
  unsigned wb = s & ~15u;
  const uint4* pR = reinterpret_cast<const uint4*>(tR + wb);
  const uint4* pI = reinterpret_cast<const uint4*>(tI + wb);
  uint4 a = pR[0], b = pR[1];
  uint4 c = pI[0], d = pI[1];
  unsigned r0, r1, r2, r3, i0, i1, i2, i3;
  switch ((s >> 2) & 3u) {
    case 0:  // 0,5,10,15
      r0 = a.x & 0xFFFFu; r1 = a.z >> 16; r2 = b.y & 0xFFFFu; r3 = b.w >> 16;
      i0 = c.x & 0xFFFFu; i1 = c.z >> 16; i2 = d.y & 0xFFFFu; i3 = d.w >> 16;
      break;
    case 1:  // 4,1,14,11
      r0 = a.z & 0xFFFFu; r1 = a.x >> 16; r2 = b.w & 0xFFFFu; r3 = b.y >> 16;
      i0 = c.z & 0xFFFFu; i1 = c.x >> 16; i2 = d.w & 0xFFFFu; i3 = d.y >> 16;
      break;
    case 2:  // 8,13,2,7
      r0 = b.x & 0xFFFFu; r1 = b.z >> 16; r2 = a.y & 0xFFFFu; r3 = a.w >> 16;
      i0 = d.x & 0xFFFFu; i1 = d.z >> 16; i2 = c.y & 0xFFFFu; i3 = c.w >> 16;
      break;
    default: // 12,9,6,3
      r0 = b.z & 0xFFFFu; r1 = b.x >> 16; r2 = a.w & 0xFFFFu; r3 = a.y >> 16;
      i0 = d.z & 0xFFFFu; i1 = d.x >> 16; i2 = c.w & 0xFFFFu; i3 = c.y >> 16;
      break;
  }
  *reinterpret_cast<uint4*>(out32 + lb) =
      make_uint4(r0 | (i0 << 16), r1 | (i1 << 16),
                 r2 | (i2 << 16), r3 | (i3 << 16));
}

// ---------------- proven tier-C fallback (R6) ----------------
__global__ void __launch_bounds__(256)
kinit(const void* s0, const void* s1, float* d0, float* d1,
      const int* __restrict__ flag, int basepl) {
  int pl = blockIdx.y + basepl;
  int f = *flag;
  const void* src = (pl ^ (f ? 0 : 1)) ? s1 : s0;
  float* dst = pl ? d1 : d0;
  unsigned p = blockIdx.x * 256 + threadIdx.x;
  unsigned q = (p ^ (p << 2)) & IDXMASK;
  dst[p] = f ? bf2f(((const unsigned short*)src)[q]) : ((const float*)src)[q];
}
__global__ void __launch_bounds__(256)
kpass(float* b0, float* b1, const float* __restrict__ csb,
      int L, int qa, unsigned ma, unsigned mb) {
  int k = L * 22 + qa;
  float ca = csb[k], sa = csb[66 + k];
  float cb = csb[k + 1], sb = csb[66 + k + 1];
  float* buf = blockIdx.y ? b1 : b0;
  unsigned t = blockIdx.x * 256 + threadIdx.x;
  unsigned j = (t & ((1u << qa) - 1u)) | ((t >> qa) << (qa + 2));
  unsigned p = j;
  if (L == 0)      { p ^= p << 2; p ^= p << 4; p ^= p << 8; p ^= p << 16; }
  else if (L == 1) { p ^= p << 1; p ^= p << 2; p ^= p << 4; p ^= p << 8; p ^= p << 16; }
  p &= IDXMASK;
  unsigned mc = ma ^ mb;
  float x0 = buf[p], x1 = buf[p ^ ma], x2 = buf[p ^ mb], x3 = buf[p ^ mc];
  float y0 = ca * x0 - sa * x1, y1 = sa * x0 + ca * x1;
  float y2 = ca * x2 - sa * x3, y3 = sa * x2 + ca * x3;
  buf[p]      = cb * y0 - sb * y2;
  buf[p ^ ma] = cb * y1 - sb * y3;
  buf[p ^ mb] = sb * y0 + cb * y2;
  buf[p ^ mc] = sb * y1 + cb * y3;
}
__global__ void __launch_bounds__(256)
kpark(const float* __restrict__ fv, unsigned short* __restrict__ park) {
  unsigned j = blockIdx.x * 256 + threadIdx.x;
  park[j] = f2bf(fv[j]);
}
__global__ void __launch_bounds__(256)
kmerge(const unsigned short* __restrict__ park, unsigned int* outw) {
  unsigned j = blockIdx.x * 256 + threadIdx.x;
  float vv = __uint_as_float(outw[j]);
  outw[j] = (unsigned)park[j] | ((unsigned)f2bf(vv) << 16);
}
static inline unsigned pmask(int q, int L) {
  unsigned r = 0;
  if (L == 0)      for (unsigned m = 1u << q; m < NSTATES; m <<= 2) r ^= m;
  else if (L == 1) for (unsigned m = 1u << q; m < NSTATES; m <<= 1) r ^= m;
  else r = 1u << q;
  return r;
}

extern "C" void kernel_launch(void* const* d_in, const int* in_sizes, int n_in,
                              void* d_out, int out_size, void* d_ws, size_t ws_size,
                              hipStream_t stream) {
  (void)out_size;
  const void* prm = d_in[0];
  const void* re  = d_in[1];
  const void* im  = d_in[2];
  if (in_sizes[0] != 66) {   // defensive size-based remap
    const void* big[2] = {nullptr, nullptr};
    int nb = 0;
    for (int i = 0; i < n_in; ++i) {
      if (in_sizes[i] == 66) prm = d_in[i];
      else if (nb < 2) big[nb++] = d_in[i];
    }
    if (nb == 2) { re = big[0]; im = big[1]; }
  }
  const size_t N = NSTATES;

  if (ws_size >= N * 12 + 1024) {
    // ---- fast path: 2 sweeps + gather ----
    float* Wr = (float*)d_ws;
    float* Wi = Wr + N;
    unsigned short* tR = (unsigned short*)(Wi + N);
    unsigned short* tI = tR + N;
    float* csb = (float*)(tI + N);
    int* flag = (int*)(csb + 140);
    ksetup<<<1, 256, 0, stream>>>((const unsigned int*)re, prm, csb, flag);
    ksweep1<<<dim3(512, 2), 256, 0, stream>>>(re, im, Wr, Wi, csb, flag);
    ksweep2<<<dim3(512, 2), 256, 0, stream>>>(Wr, Wi, tR, tI, csb);
    kfinal<<<dim3(4096), 256, 0, stream>>>(tR, tI, (unsigned*)d_out);
  } else {
    // ---- tier C (proven R6): d_out as f32 buffer; ~8.4MB ws ----
    float* F = (float*)d_out;
    unsigned short* park = (unsigned short*)d_ws;
    float* csb = (float*)((char*)d_ws + N * 2);
    int* flag = (int*)(csb + 140);
    dim3 blk(256);
    ksetup<<<1, 256, 0, stream>>>((const unsigned int*)re, prm, csb, flag);
    kinit<<<dim3(16384, 1), blk, 0, stream>>>(re, im, F, F, flag, 0);
    for (int L = 0; L < 3; ++L)
      for (int qa = 0; qa < 22; qa += 2)
        kpass<<<dim3(4096, 1), blk, 0, stream>>>(F, F, csb, L, qa,
                                                 pmask(qa, L), pmask(qa + 1, L));
    kpark<<<dim3(16384), blk, 0, stream>>>(F, park);
    kinit<<<dim3(16384, 1), blk, 0, stream>>>(re, im, F, F, flag, 1);
    for (int L = 0; L < 3; ++L)
      for (int qa = 0; qa < 22; qa += 2)
        kpass<<<dim3(4096, 1), blk, 0, stream>>>(F, F, csb, L, qa,
                                                 pmask(qa, L), pmask(qa + 1, L));
    kmerge<<<dim3(16384), blk, 0, stream>>>(park, (unsigned int*)d_out);
  }
}

// Round 15
// 100.798 us; speedup vs baseline: 1.4692x; 1.4692x over previous
//
#include <hip/hip_runtime.h>

// 22-qubit, 3-layer RY variational circuit — forward-frame 2-sweep version.
// Real/imag planes evolve independently (all gates real).
//
// Forward frame: state in natural order; CNOT chains folded into masks/signs.
//   L0 q: mask e_q;  L1 q: mask e_q^e_{q+1}, sign parity(p_0..p_q);
//   L2 q: mask e_q^e_{q+2}, sign parity(p_q,p_{q-2},..);  out[l]=buf[sigma^2(l)].
//
// R15: sweep1 writes W' in sweep2-friendly layout [cb=p2..10][hh=p11..21][e=p0..1]
// (f32/plane) -> sweep2 stages its 32KB tile CONTIGUOUSLY (kills R14's 2.1x
// read overfetch). Sweep2 holds both planes in one 512-thr block (waves 0-3 re,
// 4-7 im), packs (re|im) u32 tmp; kfinal = R13's proven single-window gather.
// Rot schedules identical to R14 (refcheck-passing). No new roundings.

#define NQ 22
#define NSTATES (1u << NQ)
#define IDXMASK (NSTATES - 1u)

__device__ __forceinline__ unsigned short f2bf(float x) {
  unsigned int b = __float_as_uint(x);
  b += 0x7FFFu + ((b >> 16) & 1u);   // round-to-nearest-even
  return (unsigned short)(b >> 16);
}
__device__ __forceinline__ float bf2f(unsigned short h) {
  return __uint_as_float((unsigned int)h << 16);
}
// LDS swizzle for 13-bit local index: bank bits 0..4 ^= l5..9 ^ l10..12.
__device__ __forceinline__ unsigned SW(unsigned l) {
  return l ^ ((l >> 5) & 31u) ^ ((l >> 10) & 7u);
}

// Generalized RY butterfly (pair enumeration by LOWEST set bit of MR).
template <int ML, int MR, int RS, unsigned SM>
__device__ __forceinline__ void rot(float (&v)[32], float c, float s, unsigned pbase) {
  int sb = __popc(pbase & SM) & 1;
  float sp = sb ? s : -s;
  constexpr int LB = MR & (-MR);
  if (ML == 0) {
#pragma unroll
    for (int i = 0; i < 32; ++i)
      if (!(i & LB)) {
        const int j = i ^ MR;
        const int pi = __builtin_popcount(((unsigned)i << RS) & SM) & 1;
        const int pj = __builtin_popcount(((unsigned)j << RS) & SM) & 1;
        float a = v[i], b = v[j];
        v[i] = fmaf(pi ? -sp : sp, b, c * a);
        v[j] = fmaf(pj ? -sp : sp, a, c * b);
      }
  } else if (MR == 0) {
#pragma unroll
    for (int i = 0; i < 32; ++i) {
      float o = __shfl_xor(v[i], ML, 64);
      const int pi = __builtin_popcount(((unsigned)i << RS) & SM) & 1;
      v[i] = fmaf(pi ? -sp : sp, o, c * v[i]);
    }
  } else {
#pragma unroll
    for (int i = 0; i < 32; ++i)
      if (!(i & LB)) {
        const int j = i ^ MR;
        float oa = __shfl_xor(v[j], ML, 64);
        float ob = __shfl_xor(v[i], ML, 64);
        const int pi = __builtin_popcount(((unsigned)i << RS) & SM) & 1;
        const int pj = __builtin_popcount(((unsigned)j << RS) & SM) & 1;
        v[i] = fmaf(pi ? -sp : sp, oa, c * v[i]);
        v[j] = fmaf(pj ? -sp : sp, ob, c * v[j]);
      }
  }
}

// setup: input dtype flag + 66 sincos pairs
__global__ void ksetup(const unsigned int* __restrict__ probe,
                       const void* __restrict__ prm,
                       float* __restrict__ csb, int* __restrict__ flagp) {
  __shared__ int anybad;
  if (threadIdx.x == 0) anybad = 0;
  __syncthreads();
  int bad = 0;
  for (int i = threadIdx.x; i < 4096; i += 256) {
    unsigned e = (probe[i] >> 7) & 0xFFu;
    bad |= (e >= 0x90u);
  }
  if (bad) anybad = 1;
  __syncthreads();
  int f = anybad ? 0 : 1;
  if (threadIdx.x == 0) *flagp = f;
  int i = threadIdx.x;
  if (i < 66) {
    float a = f ? bf2f(((const unsigned short*)prm)[i]) : ((const float*)prm)[i];
    float sv, cv;
    sincosf(0.5f * a, &sv, &cv);
    csb[i] = cv; csb[66 + i] = sv;
  }
}

#define RC(k) csb[k], csb[66 + (k)]

// ---- sweep 1: masks within bits 0..12 (36 gates) ----
// tile = 2^13 f32 (32KB LDS), 256 threads, 5 blocks/CU. B = blockIdx.x = p13..21.
// A/C layout: regs=l8..12, lane=l2..7, wv=l0..1;  B layout: regs=l0..4, lane=l5..10, wv=l11..12.
// Store: W'[cb9=p2..10][hh=p11..21][e=p0..1] f32, hh = h2 | B<<2.
__global__ void __launch_bounds__(256, 5)
ksweep1(const void* re, const void* im, float* __restrict__ Wr,
        float* __restrict__ Wi, const float* __restrict__ csb,
        const int* __restrict__ flag) {
  __shared__ float ld[8192];
  int tid = threadIdx.x;
  int f = *flag;
  int pl = blockIdx.y;
  const void* src = (pl ^ (f ? 0 : 1)) ? im : re;
  float* W = pl ? Wi : Wr;
  unsigned B = blockIdx.x;
  unsigned tb = B << 13;

  if (f) {
    const unsigned short* sp = (const unsigned short*)src + tb;
#pragma unroll
    for (int k = 0; k < 4; ++k) {
      unsigned C = (unsigned)k * 256 + tid;       // 16B chunk = 8 bf16
      uint4 q = *reinterpret_cast<const uint4*>(sp + C * 8);
      unsigned e0 = C * 8;
      ld[SW(e0 + 0)] = bf2f((unsigned short)(q.x & 0xFFFFu));
      ld[SW(e0 + 1)] = bf2f((unsigned short)(q.x >> 16));
      ld[SW(e0 + 2)] = bf2f((unsigned short)(q.y & 0xFFFFu));
      ld[SW(e0 + 3)] = bf2f((unsigned short)(q.y >> 16));
      ld[SW(e0 + 4)] = bf2f((unsigned short)(q.z & 0xFFFFu));
      ld[SW(e0 + 5)] = bf2f((unsigned short)(q.z >> 16));
      ld[SW(e0 + 6)] = bf2f((unsigned short)(q.w & 0xFFFFu));
      ld[SW(e0 + 7)] = bf2f((unsigned short)(q.w >> 16));
    }
  } else {
    const float* sp = (const float*)src + tb;
#pragma unroll
    for (int k = 0; k < 8; ++k) {
      unsigned C = (unsigned)k * 256 + tid;       // 16B chunk = 4 f32
      float4 t = *reinterpret_cast<const float4*>(sp + C * 4);
      unsigned e0 = C * 4;
      ld[SW(e0 + 0)] = t.x; ld[SW(e0 + 1)] = t.y;
      ld[SW(e0 + 2)] = t.z; ld[SW(e0 + 3)] = t.w;
    }
  }
  __syncthreads();

  int lane = tid & 63, wv = tid >> 6;              // wv 0..3
  unsigned lbA = (unsigned)wv | ((unsigned)lane << 2);
  unsigned pbA = tb | lbA;
  float v[32];

  // ---- phase A: L0 q2..12 ----
#pragma unroll
  for (int i = 0; i < 32; ++i) v[i] = ld[SW(lbA | ((unsigned)i << 8))];
  rot<1, 0, 8, (1u << 2)>(v, RC(2), pbA);
  rot<2, 0, 8, (1u << 3)>(v, RC(3), pbA);
  rot<4, 0, 8, (1u << 4)>(v, RC(4), pbA);
  rot<8, 0, 8, (1u << 5)>(v, RC(5), pbA);
  rot<16, 0, 8, (1u << 6)>(v, RC(6), pbA);
  rot<32, 0, 8, (1u << 7)>(v, RC(7), pbA);
  rot<0, 1, 8, (1u << 8)>(v, RC(8), pbA);
  rot<0, 2, 8, (1u << 9)>(v, RC(9), pbA);
  rot<0, 4, 8, (1u << 10)>(v, RC(10), pbA);
  rot<0, 8, 8, (1u << 11)>(v, RC(11), pbA);
  rot<0, 16, 8, (1u << 12)>(v, RC(12), pbA);
#pragma unroll
  for (int i = 0; i < 32; ++i) ld[SW(lbA | ((unsigned)i << 8))] = v[i];
  __syncthreads();

  // ---- phase B: L0 q0,1; L1 q0..9; L2 q0..8 ----
  unsigned lbB = ((unsigned)lane << 5) | ((unsigned)wv << 11);
  unsigned pbB = tb | lbB;
#pragma unroll
  for (int i = 0; i < 32; ++i) v[i] = ld[SW(lbB | (unsigned)i)];
  rot<0, 1, 0, 0x1u>(v, RC(0), pbB);
  rot<0, 2, 0, 0x2u>(v, RC(1), pbB);
  rot<0, 3, 0, 0x1u>(v, RC(22), pbB);
  rot<0, 6, 0, 0x3u>(v, RC(23), pbB);
  rot<0, 12, 0, 0x7u>(v, RC(24), pbB);
  rot<0, 24, 0, 0xFu>(v, RC(25), pbB);
  rot<1, 16, 0, 0x1Fu>(v, RC(26), pbB);
  rot<3, 0, 0, 0x3Fu>(v, RC(27), pbB);
  rot<6, 0, 0, 0x7Fu>(v, RC(28), pbB);
  rot<12, 0, 0, 0xFFu>(v, RC(29), pbB);
  rot<24, 0, 0, 0x1FFu>(v, RC(30), pbB);
  rot<48, 0, 0, 0x3FFu>(v, RC(31), pbB);
  rot<0, 5, 0, 0x1u>(v, RC(44), pbB);
  rot<0, 10, 0, 0x2u>(v, RC(45), pbB);
  rot<0, 20, 0, 0x5u>(v, RC(46), pbB);
  rot<1, 8, 0, 0xAu>(v, RC(47), pbB);
  rot<2, 16, 0, 0x15u>(v, RC(48), pbB);
  rot<5, 0, 0, 0x2Au>(v, RC(49), pbB);
  rot<10, 0, 0, 0x55u>(v, RC(50), pbB);
  rot<20, 0, 0, 0xAAu>(v, RC(51), pbB);
  rot<40, 0, 0, 0x155u>(v, RC(52), pbB);
#pragma unroll
  for (int i = 0; i < 32; ++i) ld[SW(lbB | (unsigned)i)] = v[i];
  __syncthreads();

  // ---- phase C (= A layout): L1 q10,11; L2 q9,10 ----
#pragma unroll
  for (int i = 0; i < 32; ++i) v[i] = ld[SW(lbA | ((unsigned)i << 8))];
  rot<0, 12, 8, 0x7FFu>(v, RC(32), pbA);
  rot<0, 24, 8, 0xFFFu>(v, RC(33), pbA);
  rot<0, 10, 8, 0x2AAu>(v, RC(53), pbA);
  rot<0, 20, 8, 0x555u>(v, RC(54), pbA);
#pragma unroll
  for (int i = 0; i < 32; ++i) ld[SW(lbA | ((unsigned)i << 8))] = v[i];
  __syncthreads();

  // ---- store to W' [cb9<<13 | B<<4 | h2<<2 | e] ----
#pragma unroll
  for (int k = 0; k < 8; ++k) {
    unsigned c = (unsigned)k * 256 + tid;   // 0..2047
    unsigned cb9 = c >> 2, h2 = c & 3;
    unsigned lloc = (cb9 << 2) | (h2 << 11);
    float4 t;
    t.x = ld[SW(lloc | 0)];
    t.y = ld[SW(lloc | 1)];
    t.z = ld[SW(lloc | 2)];
    t.w = ld[SW(lloc | 3)];
    *reinterpret_cast<float4*>(W + (((size_t)cb9 << 13) | ((size_t)B << 4) |
                                    (h2 << 2))) = t;
  }
}

// ---- sweep 2: masks within bits 11..21 (30 gates), both planes in-block ----
// block cb = p2..10; tile/plane = 2048 hh (p11..21) x 4 e (p0..1) = 32KB.
// stage = CONTIGUOUS 32KB per plane from W'. waves 0-3: re, 4-7: im.
// layout: regs=h6..10 (p17..21), lane=h0..5 (p11..16), wv&3=e.
__global__ void __launch_bounds__(512)
ksweep2(const float* __restrict__ Wr, const float* __restrict__ Wi,
        unsigned* __restrict__ tmp, const float* __restrict__ csb) {
  __shared__ float ld[2][8192];
  int tid = threadIdx.x;
  unsigned cb = blockIdx.x;             // p2..10

  // stage: 4096 contiguous 16B chunks (2048/plane)
#pragma unroll
  for (int k = 0; k < 8; ++k) {
    unsigned C = (unsigned)k * 512 + tid;   // 0..4095
    int p = C >> 11;
    unsigned hh = C & 2047u;
    const float* W = p ? Wi : Wr;
    float4 t = *reinterpret_cast<const float4*>(W + (((size_t)cb << 13) |
                                                     (hh << 2)));
    unsigned e0 = hh << 2;
    ld[p][SW(e0 + 0)] = t.x; ld[p][SW(e0 + 1)] = t.y;
    ld[p][SW(e0 + 2)] = t.z; ld[p][SW(e0 + 3)] = t.w;
  }
  __syncthreads();

  int lane = tid & 63;
  int wv = (tid >> 6) & 3;              // e = p0..1
  int pl = tid >> 8;                    // plane
  float* L = ld[pl];
  unsigned lbD = (unsigned)wv | ((unsigned)lane << 2);
  unsigned pbD = (unsigned)wv | (cb << 2) | ((unsigned)lane << 11);
  float v[32];
#pragma unroll
  for (int i = 0; i < 32; ++i) v[i] = L[SW(lbD | ((unsigned)i << 8))];
  // L0 q13..21
  rot<4, 0, 17, (1u << 13)>(v, RC(13), pbD);
  rot<8, 0, 17, (1u << 14)>(v, RC(14), pbD);
  rot<16, 0, 17, (1u << 15)>(v, RC(15), pbD);
  rot<32, 0, 17, (1u << 16)>(v, RC(16), pbD);
  rot<0, 1, 17, (1u << 17)>(v, RC(17), pbD);
  rot<0, 2, 17, (1u << 18)>(v, RC(18), pbD);
  rot<0, 4, 17, (1u << 19)>(v, RC(19), pbD);
  rot<0, 8, 17, (1u << 20)>(v, RC(20), pbD);
  rot<0, 16, 17, (1u << 21)>(v, RC(21), pbD);
  // L1 q12..21
  rot<6, 0, 17, 0x1FFFu>(v, RC(34), pbD);
  rot<12, 0, 17, 0x3FFFu>(v, RC(35), pbD);
  rot<24, 0, 17, 0x7FFFu>(v, RC(36), pbD);
  rot<48, 0, 17, 0xFFFFu>(v, RC(37), pbD);
  rot<32, 1, 17, 0x1FFFFu>(v, RC(38), pbD);
  rot<0, 3, 17, 0x3FFFFu>(v, RC(39), pbD);
  rot<0, 6, 17, 0x7FFFFu>(v, RC(40), pbD);
  rot<0, 12, 17, 0xFFFFFu>(v, RC(41), pbD);
  rot<0, 24, 17, 0x1FFFFFu>(v, RC(42), pbD);
  rot<0, 16, 17, 0x3FFFFFu>(v, RC(43), pbD);
  // L2 q11..21
  rot<5, 0, 17, 0xAAAu>(v, RC(55), pbD);
  rot<10, 0, 17, 0x1555u>(v, RC(56), pbD);
  rot<20, 0, 17, 0x2AAAu>(v, RC(57), pbD);
  rot<40, 0, 17, 0x5555u>(v, RC(58), pbD);
  rot<16, 1, 17, 0xAAAAu>(v, RC(59), pbD);
  rot<32, 2, 17, 0x15555u>(v, RC(60), pbD);
  rot<0, 5, 17, 0x2AAAAu>(v, RC(61), pbD);
  rot<0, 10, 17, 0x55555u>(v, RC(62), pbD);
  rot<0, 20, 17, 0xAAAAAu>(v, RC(63), pbD);
  rot<0, 8, 17, 0x155555u>(v, RC(64), pbD);
  rot<0, 16, 17, 0x2AAAAAu>(v, RC(65), pbD);
#pragma unroll
  for (int i = 0; i < 32; ++i) L[SW(lbD | ((unsigned)i << 8))] = v[i];
  __syncthreads();

  // pack both planes -> p-linear u32 tmp: p = e | cb<<2 | hh<<11
#pragma unroll
  for (int k = 0; k < 4; ++k) {
    unsigned Q = (unsigned)k * 512 + tid;   // hh
    unsigned e0 = Q << 2;
    uint4 o;
    o.x = (unsigned)f2bf(ld[0][SW(e0 + 0)]) | ((unsigned)f2bf(ld[1][SW(e0 + 0)]) << 16);
    o.y = (unsigned)f2bf(ld[0][SW(e0 + 1)]) | ((unsigned)f2bf(ld[1][SW(e0 + 1)]) << 16);
    o.z = (unsigned)f2bf(ld[0][SW(e0 + 2)]) | ((unsigned)f2bf(ld[1][SW(e0 + 2)]) << 16);
    o.w = (unsigned)f2bf(ld[0][SW(e0 + 3)]) | ((unsigned)f2bf(ld[1][SW(e0 + 3)]) << 16);
    *reinterpret_cast<uint4*>(tmp + (((size_t)Q << 11) | (cb << 2))) = o;
  }
}

// ---- final gather: out[l] = tmp[sigma^2(l)] (R13-proven) ----
__global__ void __launch_bounds__(256)
kfinal(const unsigned* __restrict__ tmp, unsigned* __restrict__ out32) {
  unsigned T = blockIdx.x * 256 + threadIdx.x;   // quad id [0, 2^20)
  unsigned lb = T << 2;
  unsigned s = (lb ^ (lb << 2)) & IDXMASK;       // %4 == 0
  const uint4* w = reinterpret_cast<const uint4*>(tmp + (s & ~15u));
  uint4 a = w[0], b = w[1], c = w[2], d = w[3];
  uint4 o;
  switch ((s >> 2) & 3u) {
    case 0: o = make_uint4(a.x, b.y, c.z, d.w); break;   // 0,5,10,15
    case 1: o = make_uint4(b.x, a.y, d.z, c.w); break;   // 4,1,14,11
    case 2: o = make_uint4(c.x, d.y, a.z, b.w); break;   // 8,13,2,7
    default: o = make_uint4(d.x, c.y, b.z, a.w); break;  // 12,9,6,3
  }
  *reinterpret_cast<uint4*>(out32 + lb) = o;
}

// ---------------- proven tier-C fallback (R6) ----------------
__global__ void __launch_bounds__(256)
kinit(const void* s0, const void* s1, float* d0, float* d1,
      const int* __restrict__ flag, int basepl) {
  int pl = blockIdx.y + basepl;
  int f = *flag;
  const void* src = (pl ^ (f ? 0 : 1)) ? s1 : s0;
  float* dst = pl ? d1 : d0;
  unsigned p = blockIdx.x * 256 + threadIdx.x;
  unsigned q = (p ^ (p << 2)) & IDXMASK;
  dst[p] = f ? bf2f(((const unsigned short*)src)[q]) : ((const float*)src)[q];
}
__global__ void __launch_bounds__(256)
kpass(float* b0, float* b1, const float* __restrict__ csb,
      int L, int qa, unsigned ma, unsigned mb) {
  int k = L * 22 + qa;
  float ca = csb[k], sa = csb[66 + k];
  float cb = csb[k + 1], sb = csb[66 + k + 1];
  float* buf = blockIdx.y ? b1 : b0;
  unsigned t = blockIdx.x * 256 + threadIdx.x;
  unsigned j = (t & ((1u << qa) - 1u)) | ((t >> qa) << (qa + 2));
  unsigned p = j;
  if (L == 0)      { p ^= p << 2; p ^= p << 4; p ^= p << 8; p ^= p << 16; }
  else if (L == 1) { p ^= p << 1; p ^= p << 2; p ^= p << 4; p ^= p << 8; p ^= p << 16; }
  p &= IDXMASK;
  unsigned mc = ma ^ mb;
  float x0 = buf[p], x1 = buf[p ^ ma], x2 = buf[p ^ mb], x3 = buf[p ^ mc];
  float y0 = ca * x0 - sa * x1, y1 = sa * x0 + ca * x1;
  float y2 = ca * x2 - sa * x3, y3 = sa * x2 + ca * x3;
  buf[p]      = cb * y0 - sb * y2;
  buf[p ^ ma] = cb * y1 - sb * y3;
  buf[p ^ mb] = sb * y0 + cb * y2;
  buf[p ^ mc] = sb * y1 + cb * y3;
}
__global__ void __launch_bounds__(256)
kpark(const float* __restrict__ fv, unsigned short* __restrict__ park) {
  unsigned j = blockIdx.x * 256 + threadIdx.x;
  park[j] = f2bf(fv[j]);
}
__global__ void __launch_bounds__(256)
kmerge(const unsigned short* __restrict__ park, unsigned int* outw) {
  unsigned j = blockIdx.x * 256 + threadIdx.x;
  float vv = __uint_as_float(outw[j]);
  outw[j] = (unsigned)park[j] | ((unsigned)f2bf(vv) << 16);
}
static inline unsigned pmask(int q, int L) {
  unsigned r = 0;
  if (L == 0)      for (unsigned m = 1u << q; m < NSTATES; m <<= 2) r ^= m;
  else if (L == 1) for (unsigned m = 1u << q; m < NSTATES; m <<= 1) r ^= m;
  else r = 1u << q;
  return r;
}

extern "C" void kernel_launch(void* const* d_in, const int* in_sizes, int n_in,
                              void* d_out, int out_size, void* d_ws, size_t ws_size,
                              hipStream_t stream) {
  (void)out_size;
  const void* prm = d_in[0];
  const void* re  = d_in[1];
  const void* im  = d_in[2];
  if (in_sizes[0] != 66) {   // defensive size-based remap
    const void* big[2] = {nullptr, nullptr};
    int nb = 0;
    for (int i = 0; i < n_in; ++i) {
      if (in_sizes[i] == 66) prm = d_in[i];
      else if (nb < 2) big[nb++] = d_in[i];
    }
    if (nb == 2) { re = big[0]; im = big[1]; }
  }
  const size_t N = NSTATES;

  if (ws_size >= N * 12 + 1024) {
    // ---- fast path: 2 sweeps + gather ----
    float* Wr = (float*)d_ws;
    float* Wi = Wr + N;
    unsigned* tmp = (unsigned*)(Wi + N);
    float* csb = (float*)(tmp + N);
    int* flag = (int*)(csb + 140);
    ksetup<<<1, 256, 0, stream>>>((const unsigned int*)re, prm, csb, flag);
    ksweep1<<<dim3(512, 2), 256, 0, stream>>>(re, im, Wr, Wi, csb, flag);
    ksweep2<<<dim3(512), 512, 0, stream>>>(Wr, Wi, tmp, csb);
    kfinal<<<dim3(4096), 256, 0, stream>>>(tmp, (unsigned*)d_out);
  } else {
    // ---- tier C (proven R6): d_out as f32 buffer; ~8.4MB ws ----
    float* F = (float*)d_out;
    unsigned short* park = (unsigned short*)d_ws;
    float* csb = (float*)((char*)d_ws + N * 2);
    int* flag = (int*)(csb + 140);
    dim3 blk(256);
    ksetup<<<1, 256, 0, stream>>>((const unsigned int*)re, prm, csb, flag);
    kinit<<<dim3(16384, 1), blk, 0, stream>>>(re, im, F, F, flag, 0);
    for (int L = 0; L < 3; ++L)
      for (int qa = 0; qa < 22; qa += 2)
        kpass<<<dim3(4096, 1), blk, 0, stream>>>(F, F, csb, L, qa,
                                                 pmask(qa, L), pmask(qa + 1, L));
    kpark<<<dim3(16384), blk, 0, stream>>>(F, park);
    kinit<<<dim3(16384, 1), blk, 0, stream>>>(re, im, F, F, flag, 1);
    for (int L = 0; L < 3; ++L)
      for (int qa = 0; qa < 22; qa += 2)
        kpass<<<dim3(4096, 1), blk, 0, stream>>>(F, F, csb, L, qa,
                                                 pmask(qa, L), pmask(qa + 1, L));
    kmerge<<<dim3(16384), blk, 0, stream>>>(park, (unsigned int*)d_out);
  }
}

// Round 16
// 97.314 us; speedup vs baseline: 1.5218x; 1.0358x over previous
//
#include <hip/hip_runtime.h>

// 22-qubit, 3-layer RY variational circuit — forward-frame 2-sweep version.
// Real/imag planes evolve independently (all gates real).
//
// Forward frame: state in natural order; CNOT chains folded into masks/signs.
//   L0 q: mask e_q;  L1 q: mask e_q^e_{q+1}, sign parity(p_0..p_q);
//   L2 q: mask e_q^e_{q+2}, sign parity(p_q,p_{q-2},..);  out[l]=buf[sigma^2(l)].
//
// R16: ksweep1 restructured to 512 threads (8 waves), 16 elems/thread, same
// 32KB tile -> 4 blocks/CU = 32 waves/CU (was 16). 3-phase schedule re-derived
// for 4-bit reg dim; all reorderings re-verified (f1(m2)==f2(m1)==0).
// ksweep2 / kfinal / tier-C unchanged from R15 (passing, absmax 0.031).

#define NQ 22
#define NSTATES (1u << NQ)
#define IDXMASK (NSTATES - 1u)

__device__ __forceinline__ unsigned short f2bf(float x) {
  unsigned int b = __float_as_uint(x);
  b += 0x7FFFu + ((b >> 16) & 1u);   // round-to-nearest-even
  return (unsigned short)(b >> 16);
}
__device__ __forceinline__ float bf2f(unsigned short h) {
  return __uint_as_float((unsigned int)h << 16);
}
// LDS swizzle for 13-bit local index: bank bits 0..4 ^= l5..9 ^ l10..12.
__device__ __forceinline__ unsigned SW(unsigned l) {
  return l ^ ((l >> 5) & 31u) ^ ((l >> 10) & 7u);
}

// Generalized RY butterfly (pair enumeration by LOWEST set bit of MR).
// N = register-array length (16 for sweep1, 32 for sweep2), deduced.
template <int ML, int MR, int RS, unsigned SM, int N>
__device__ __forceinline__ void rot(float (&v)[N], float c, float s, unsigned pbase) {
  int sb = __popc(pbase & SM) & 1;
  float sp = sb ? s : -s;
  constexpr int LB = MR & (-MR);
  if (ML == 0) {
#pragma unroll
    for (int i = 0; i < N; ++i)
      if (!(i & LB)) {
        const int j = i ^ MR;
        const int pi = __builtin_popcount(((unsigned)i << RS) & SM) & 1;
        const int pj = __builtin_popcount(((unsigned)j << RS) & SM) & 1;
        float a = v[i], b = v[j];
        v[i] = fmaf(pi ? -sp : sp, b, c * a);
        v[j] = fmaf(pj ? -sp : sp, a, c * b);
      }
  } else if (MR == 0) {
#pragma unroll
    for (int i = 0; i < N; ++i) {
      float o = __shfl_xor(v[i], ML, 64);
      const int pi = __builtin_popcount(((unsigned)i << RS) & SM) & 1;
      v[i] = fmaf(pi ? -sp : sp, o, c * v[i]);
    }
  } else {
#pragma unroll
    for (int i = 0; i < N; ++i)
      if (!(i & LB)) {
        const int j = i ^ MR;
        float oa = __shfl_xor(v[j], ML, 64);
        float ob = __shfl_xor(v[i], ML, 64);
        const int pi = __builtin_popcount(((unsigned)i << RS) & SM) & 1;
        const int pj = __builtin_popcount(((unsigned)j << RS) & SM) & 1;
        v[i] = fmaf(pi ? -sp : sp, oa, c * v[i]);
        v[j] = fmaf(pj ? -sp : sp, ob, c * v[j]);
      }
  }
}

// setup: input dtype flag + 66 sincos pairs
__global__ void ksetup(const unsigned int* __restrict__ probe,
                       const void* __restrict__ prm,
                       float* __restrict__ csb, int* __restrict__ flagp) {
  __shared__ int anybad;
  if (threadIdx.x == 0) anybad = 0;
  __syncthreads();
  int bad = 0;
  for (int i = threadIdx.x; i < 4096; i += 256) {
    unsigned e = (probe[i] >> 7) & 0xFFu;
    bad |= (e >= 0x90u);
  }
  if (bad) anybad = 1;
  __syncthreads();
  int f = anybad ? 0 : 1;
  if (threadIdx.x == 0) *flagp = f;
  int i = threadIdx.x;
  if (i < 66) {
    float a = f ? bf2f(((const unsigned short*)prm)[i]) : ((const float*)prm)[i];
    float sv, cv;
    sincosf(0.5f * a, &sv, &cv);
    csb[i] = cv; csb[66 + i] = sv;
  }
}

#define RC(k) csb[k], csb[66 + (k)]

// ---- sweep 1: masks within bits 0..12 (36 gates) ----
// 512 threads (8 waves), tile = 2^13 f32 (32KB LDS), 16 elems/thread,
// 4 blocks/CU = 32 waves/CU. B(block) = p13..21.
// Phase A/C layout: regs=l9..12, lane=l3..8, wv=l0..2
// Phase B layout:   regs=l0..3,  lane=l4..9, wv=l10..12
// Store: W'[cb9=p2..10][B=p13..21][h2=p11..12][e=p0..1] f32.
__global__ void __launch_bounds__(512, 8)
ksweep1(const void* re, const void* im, float* __restrict__ Wr,
        float* __restrict__ Wi, const float* __restrict__ csb,
        const int* __restrict__ flag) {
  __shared__ float ld[8192];
  int tid = threadIdx.x;
  int f = *flag;
  int pl = blockIdx.y;
  const void* src = (pl ^ (f ? 0 : 1)) ? im : re;
  float* W = pl ? Wi : Wr;
  unsigned B = blockIdx.x;
  unsigned tb = B << 13;

  if (f) {
    const unsigned short* sp = (const unsigned short*)src + tb;
#pragma unroll
    for (int k = 0; k < 2; ++k) {
      unsigned C = (unsigned)k * 512 + tid;       // 16B chunk = 8 bf16
      uint4 q = *reinterpret_cast<const uint4*>(sp + C * 8);
      unsigned e0 = C * 8;
      ld[SW(e0 + 0)] = bf2f((unsigned short)(q.x & 0xFFFFu));
      ld[SW(e0 + 1)] = bf2f((unsigned short)(q.x >> 16));
      ld[SW(e0 + 2)] = bf2f((unsigned short)(q.y & 0xFFFFu));
      ld[SW(e0 + 3)] = bf2f((unsigned short)(q.y >> 16));
      ld[SW(e0 + 4)] = bf2f((unsigned short)(q.z & 0xFFFFu));
      ld[SW(e0 + 5)] = bf2f((unsigned short)(q.z >> 16));
      ld[SW(e0 + 6)] = bf2f((unsigned short)(q.w & 0xFFFFu));
      ld[SW(e0 + 7)] = bf2f((unsigned short)(q.w >> 16));
    }
  } else {
    const float* sp = (const float*)src + tb;
#pragma unroll
    for (int k = 0; k < 4; ++k) {
      unsigned C = (unsigned)k * 512 + tid;       // 16B chunk = 4 f32
      float4 t = *reinterpret_cast<const float4*>(sp + C * 4);
      unsigned e0 = C * 4;
      ld[SW(e0 + 0)] = t.x; ld[SW(e0 + 1)] = t.y;
      ld[SW(e0 + 2)] = t.z; ld[SW(e0 + 3)] = t.w;
    }
  }
  __syncthreads();

  int lane = tid & 63, wv = tid >> 6;              // wv 0..7
  unsigned lbA = (unsigned)wv | ((unsigned)lane << 3);
  unsigned pbA = tb | lbA;
  float v[16];

  // ---- phase A: L0 q3..q12 ----
#pragma unroll
  for (int i = 0; i < 16; ++i) v[i] = ld[SW(lbA | ((unsigned)i << 9))];
  rot<1, 0, 9, (1u << 3)>(v, RC(3), pbA);
  rot<2, 0, 9, (1u << 4)>(v, RC(4), pbA);
  rot<4, 0, 9, (1u << 5)>(v, RC(5), pbA);
  rot<8, 0, 9, (1u << 6)>(v, RC(6), pbA);
  rot<16, 0, 9, (1u << 7)>(v, RC(7), pbA);
  rot<32, 0, 9, (1u << 8)>(v, RC(8), pbA);
  rot<0, 1, 9, (1u << 9)>(v, RC(9), pbA);
  rot<0, 2, 9, (1u << 10)>(v, RC(10), pbA);
  rot<0, 4, 9, (1u << 11)>(v, RC(11), pbA);
  rot<0, 8, 9, (1u << 12)>(v, RC(12), pbA);
#pragma unroll
  for (int i = 0; i < 16; ++i) ld[SW(lbA | ((unsigned)i << 9))] = v[i];
  __syncthreads();

  // ---- phase B: L0 q0..2; L1 q0..8; L2 q0..7 ----
  unsigned lbB = ((unsigned)lane << 4) | ((unsigned)wv << 10);
  unsigned pbB = tb | lbB;
#pragma unroll
  for (int i = 0; i < 16; ++i) v[i] = ld[SW(lbB | (unsigned)i)];
  rot<0, 1, 0, 0x1u>(v, RC(0), pbB);
  rot<0, 2, 0, 0x2u>(v, RC(1), pbB);
  rot<0, 4, 0, 0x4u>(v, RC(2), pbB);
  rot<0, 3, 0, 0x1u>(v, RC(22), pbB);
  rot<0, 6, 0, 0x3u>(v, RC(23), pbB);
  rot<0, 12, 0, 0x7u>(v, RC(24), pbB);
  rot<1, 8, 0, 0xFu>(v, RC(25), pbB);
  rot<3, 0, 0, 0x1Fu>(v, RC(26), pbB);
  rot<6, 0, 0, 0x3Fu>(v, RC(27), pbB);
  rot<12, 0, 0, 0x7Fu>(v, RC(28), pbB);
  rot<24, 0, 0, 0xFFu>(v, RC(29), pbB);
  rot<48, 0, 0, 0x1FFu>(v, RC(30), pbB);
  rot<0, 5, 0, 0x1u>(v, RC(44), pbB);
  rot<0, 10, 0, 0x2u>(v, RC(45), pbB);
  rot<1, 4, 0, 0x5u>(v, RC(46), pbB);
  rot<2, 8, 0, 0xAu>(v, RC(47), pbB);
  rot<5, 0, 0, 0x15u>(v, RC(48), pbB);
  rot<10, 0, 0, 0x2Au>(v, RC(49), pbB);
  rot<20, 0, 0, 0x55u>(v, RC(50), pbB);
  rot<40, 0, 0, 0xAAu>(v, RC(51), pbB);
#pragma unroll
  for (int i = 0; i < 16; ++i) ld[SW(lbB | (unsigned)i)] = v[i];
  __syncthreads();

  // ---- phase C (= A layout): L1 q9..11; L2 q8..10 ----
#pragma unroll
  for (int i = 0; i < 16; ++i) v[i] = ld[SW(lbA | ((unsigned)i << 9))];
  rot<0, 3, 9, 0x3FFu>(v, RC(31), pbA);
  rot<0, 6, 9, 0x7FFu>(v, RC(32), pbA);
  rot<0, 12, 9, 0xFFFu>(v, RC(33), pbA);
  rot<32, 2, 9, 0x155u>(v, RC(52), pbA);
  rot<0, 5, 9, 0x2AAu>(v, RC(53), pbA);
  rot<0, 10, 9, 0x555u>(v, RC(54), pbA);
#pragma unroll
  for (int i = 0; i < 16; ++i) ld[SW(lbA | ((unsigned)i << 9))] = v[i];
  __syncthreads();

  // ---- store to W' [cb9<<13 | B<<4 | h2<<2 | e] ----
#pragma unroll
  for (int k = 0; k < 4; ++k) {
    unsigned c = (unsigned)k * 512 + tid;   // 0..2047
    unsigned cb9 = c >> 2, h2 = c & 3;
    unsigned lloc = (cb9 << 2) | (h2 << 11);
    float4 t;
    t.x = ld[SW(lloc | 0)];
    t.y = ld[SW(lloc | 1)];
    t.z = ld[SW(lloc | 2)];
    t.w = ld[SW(lloc | 3)];
    *reinterpret_cast<float4*>(W + (((size_t)cb9 << 13) | ((size_t)B << 4) |
                                    (h2 << 2))) = t;
  }
}

// ---- sweep 2: masks within bits 11..21 (30 gates), both planes in-block ----
// (unchanged from R15, passing) block cb = p2..10; tile/plane = 2048 hh x 4 e.
__global__ void __launch_bounds__(512)
ksweep2(const float* __restrict__ Wr, const float* __restrict__ Wi,
        unsigned* __restrict__ tmp, const float* __restrict__ csb) {
  __shared__ float ld[2][8192];
  int tid = threadIdx.x;
  unsigned cb = blockIdx.x;             // p2..10

#pragma unroll
  for (int k = 0; k < 8; ++k) {
    unsigned C = (unsigned)k * 512 + tid;   // 0..4095
    int p = C >> 11;
    unsigned hh = C & 2047u;
    const float* W = p ? Wi : Wr;
    float4 t = *reinterpret_cast<const float4*>(W + (((size_t)cb << 13) |
                                                     (hh << 2)));
    unsigned e0 = hh << 2;
    ld[p][SW(e0 + 0)] = t.x; ld[p][SW(e0 + 1)] = t.y;
    ld[p][SW(e0 + 2)] = t.z; ld[p][SW(e0 + 3)] = t.w;
  }
  __syncthreads();

  int lane = tid & 63;
  int wv = (tid >> 6) & 3;              // e = p0..1
  int pl = tid >> 8;                    // plane
  float* L = ld[pl];
  unsigned lbD = (unsigned)wv | ((unsigned)lane << 2);
  unsigned pbD = (unsigned)wv | (cb << 2) | ((unsigned)lane << 11);
  float v[32];
#pragma unroll
  for (int i = 0; i < 32; ++i) v[i] = L[SW(lbD | ((unsigned)i << 8))];
  // L0 q13..21
  rot<4, 0, 17, (1u << 13)>(v, RC(13), pbD);
  rot<8, 0, 17, (1u << 14)>(v, RC(14), pbD);
  rot<16, 0, 17, (1u << 15)>(v, RC(15), pbD);
  rot<32, 0, 17, (1u << 16)>(v, RC(16), pbD);
  rot<0, 1, 17, (1u << 17)>(v, RC(17), pbD);
  rot<0, 2, 17, (1u << 18)>(v, RC(18), pbD);
  rot<0, 4, 17, (1u << 19)>(v, RC(19), pbD);
  rot<0, 8, 17, (1u << 20)>(v, RC(20), pbD);
  rot<0, 16, 17, (1u << 21)>(v, RC(21), pbD);
  // L1 q12..21
  rot<6, 0, 17, 0x1FFFu>(v, RC(34), pbD);
  rot<12, 0, 17, 0x3FFFu>(v, RC(35), pbD);
  rot<24, 0, 17, 0x7FFFu>(v, RC(36), pbD);
  rot<48, 0, 17, 0xFFFFu>(v, RC(37), pbD);
  rot<32, 1, 17, 0x1FFFFu>(v, RC(38), pbD);
  rot<0, 3, 17, 0x3FFFFu>(v, RC(39), pbD);
  rot<0, 6, 17, 0x7FFFFu>(v, RC(40), pbD);
  rot<0, 12, 17, 0xFFFFFu>(v, RC(41), pbD);
  rot<0, 24, 17, 0x1FFFFFu>(v, RC(42), pbD);
  rot<0, 16, 17, 0x3FFFFFu>(v, RC(43), pbD);
  // L2 q11..21
  rot<5, 0, 17, 0xAAAu>(v, RC(55), pbD);
  rot<10, 0, 17, 0x1555u>(v, RC(56), pbD);
  rot<20, 0, 17, 0x2AAAu>(v, RC(57), pbD);
  rot<40, 0, 17, 0x5555u>(v, RC(58), pbD);
  rot<16, 1, 17, 0xAAAAu>(v, RC(59), pbD);
  rot<32, 2, 17, 0x15555u>(v, RC(60), pbD);
  rot<0, 5, 17, 0x2AAAAu>(v, RC(61), pbD);
  rot<0, 10, 17, 0x55555u>(v, RC(62), pbD);
  rot<0, 20, 17, 0xAAAAAu>(v, RC(63), pbD);
  rot<0, 8, 17, 0x155555u>(v, RC(64), pbD);
  rot<0, 16, 17, 0x2AAAAAu>(v, RC(65), pbD);
#pragma unroll
  for (int i = 0; i < 32; ++i) L[SW(lbD | ((unsigned)i << 8))] = v[i];
  __syncthreads();

  // pack both planes -> p-linear u32 tmp: p = e | cb<<2 | hh<<11
#pragma unroll
  for (int k = 0; k < 4; ++k) {
    unsigned Q = (unsigned)k * 512 + tid;   // hh
    unsigned e0 = Q << 2;
    uint4 o;
    o.x = (unsigned)f2bf(ld[0][SW(e0 + 0)]) | ((unsigned)f2bf(ld[1][SW(e0 + 0)]) << 16);
    o.y = (unsigned)f2bf(ld[0][SW(e0 + 1)]) | ((unsigned)f2bf(ld[1][SW(e0 + 1)]) << 16);
    o.z = (unsigned)f2bf(ld[0][SW(e0 + 2)]) | ((unsigned)f2bf(ld[1][SW(e0 + 2)]) << 16);
    o.w = (unsigned)f2bf(ld[0][SW(e0 + 3)]) | ((unsigned)f2bf(ld[1][SW(e0 + 3)]) << 16);
    *reinterpret_cast<uint4*>(tmp + (((size_t)Q << 11) | (cb << 2))) = o;
  }
}

// ---- final gather: out[l] = tmp[sigma^2(l)] (R13-proven) ----
__global__ void __launch_bounds__(256)
kfinal(const unsigned* __restrict__ tmp, unsigned* __restrict__ out32) {
  unsigned T = blockIdx.x * 256 + threadIdx.x;   // quad id [0, 2^20)
  unsigned lb = T << 2;
  unsigned s = (lb ^ (lb << 2)) & IDXMASK;       // %4 == 0
  const uint4* w = reinterpret_cast<const uint4*>(tmp + (s & ~15u));
  uint4 a = w[0], b = w[1], c = w[2], d = w[3];
  uint4 o;
  switch ((s >> 2) & 3u) {
    case 0: o = make_uint4(a.x, b.y, c.z, d.w); break;   // 0,5,10,15
    case 1: o = make_uint4(b.x, a.y, d.z, c.w); break;   // 4,1,14,11
    case 2: o = make_uint4(c.x, d.y, a.z, b.w); break;   // 8,13,2,7
    default: o = make_uint4(d.x, c.y, b.z, a.w); break;  // 12,9,6,3
  }
  *reinterpret_cast<uint4*>(out32 + lb) = o;
}

// ---------------- proven tier-C fallback (R6) ----------------
__global__ void __launch_bounds__(256)
kinit(const void* s0, const void* s1, float* d0, float* d1,
      const int* __restrict__ flag, int basepl) {
  int pl = blockIdx.y + basepl;
  int f = *flag;
  const void* src = (pl ^ (f ? 0 : 1)) ? s1 : s0;
  float* dst = pl ? d1 : d0;
  unsigned p = blockIdx.x * 256 + threadIdx.x;
  unsigned q = (p ^ (p << 2)) & IDXMASK;
  dst[p] = f ? bf2f(((const unsigned short*)src)[q]) : ((const float*)src)[q];
}
__global__ void __launch_bounds__(256)
kpass(float* b0, float* b1, const float* __restrict__ csb,
      int L, int qa, unsigned ma, unsigned mb) {
  int k = L * 22 + qa;
  float ca = csb[k], sa = csb[66 + k];
  float cb = csb[k + 1], sb = csb[66 + k + 1];
  float* buf = blockIdx.y ? b1 : b0;
  unsigned t = blockIdx.x * 256 + threadIdx.x;
  unsigned j = (t & ((1u << qa) - 1u)) | ((t >> qa) << (qa + 2));
  unsigned p = j;
  if (L == 0)      { p ^= p << 2; p ^= p << 4; p ^= p << 8; p ^= p << 16; }
  else if (L == 1) { p ^= p << 1; p ^= p << 2; p ^= p << 4; p ^= p << 8; p ^= p << 16; }
  p &= IDXMASK;
  unsigned mc = ma ^ mb;
  float x0 = buf[p], x1 = buf[p ^ ma], x2 = buf[p ^ mb], x3 = buf[p ^ mc];
  float y0 = ca * x0 - sa * x1, y1 = sa * x0 + ca * x1;
  float y2 = ca * x2 - sa * x3, y3 = sa * x2 + ca * x3;
  buf[p]      = cb * y0 - sb * y2;
  buf[p ^ ma] = cb * y1 - sb * y3;
  buf[p ^ mb] = sb * y0 + cb * y2;
  buf[p ^ mc] = sb * y1 + cb * y3;
}
__global__ void __launch_bounds__(256)
kpark(const float* __restrict__ fv, unsigned short* __restrict__ park) {
  unsigned j = blockIdx.x * 256 + threadIdx.x;
  park[j] = f2bf(fv[j]);
}
__global__ void __launch_bounds__(256)
kmerge(const unsigned short* __restrict__ park, unsigned int* outw) {
  unsigned j = blockIdx.x * 256 + threadIdx.x;
  float vv = __uint_as_float(outw[j]);
  outw[j] = (unsigned)park[j] | ((unsigned)f2bf(vv) << 16);
}
static inline unsigned pmask(int q, int L) {
  unsigned r = 0;
  if (L == 0)      for (unsigned m = 1u << q; m < NSTATES; m <<= 2) r ^= m;
  else if (L == 1) for (unsigned m = 1u << q; m < NSTATES; m <<= 1) r ^= m;
  else r = 1u << q;
  return r;
}

extern "C" void kernel_launch(void* const* d_in, const int* in_sizes, int n_in,
                              void* d_out, int out_size, void* d_ws, size_t ws_size,
                              hipStream_t stream) {
  (void)out_size;
  const void* prm = d_in[0];
  const void* re  = d_in[1];
  const void* im  = d_in[2];
  if (in_sizes[0] != 66) {   // defensive size-based remap
    const void* big[2] = {nullptr, nullptr};
    int nb = 0;
    for (int i = 0; i < n_in; ++i) {
      if (in_sizes[i] == 66) prm = d_in[i];
      else if (nb < 2) big[nb++] = d_in[i];
    }
    if (nb == 2) { re = big[0]; im = big[1]; }
  }
  const size_t N = NSTATES;

  if (ws_size >= N * 12 + 1024) {
    // ---- fast path: 2 sweeps + gather ----
    float* Wr = (float*)d_ws;
    float* Wi = Wr + N;
    unsigned* tmp = (unsigned*)(Wi + N);
    float* csb = (float*)(tmp + N);
    int* flag = (int*)(csb + 140);
    ksetup<<<1, 256, 0, stream>>>((const unsigned int*)re, prm, csb, flag);
    ksweep1<<<dim3(512, 2), 512, 0, stream>>>(re, im, Wr, Wi, csb, flag);
    ksweep2<<<dim3(512), 512, 0, stream>>>(Wr, Wi, tmp, csb);
    kfinal<<<dim3(4096), 256, 0, stream>>>(tmp, (unsigned*)d_out);
  } else {
    // ---- tier C (proven R6): d_out as f32 buffer; ~8.4MB ws ----
    float* F = (float*)d_out;
    unsigned short* park = (unsigned short*)d_ws;
    float* csb = (float*)((char*)d_ws + N * 2);
    int* flag = (int*)(csb + 140);
    dim3 blk(256);
    ksetup<<<1, 256, 0, stream>>>((const unsigned int*)re, prm, csb, flag);
    kinit<<<dim3(16384, 1), blk, 0, stream>>>(re, im, F, F, flag, 0);
    for (int L = 0; L < 3; ++L)
      for (int qa = 0; qa < 22; qa += 2)
        kpass<<<dim3(4096, 1), blk, 0, stream>>>(F, F, csb, L, qa,
                                                 pmask(qa, L), pmask(qa + 1, L));
    kpark<<<dim3(16384), blk, 0, stream>>>(F, park);
    kinit<<<dim3(16384, 1), blk, 0, stream>>>(re, im, F, F, flag, 1);
    for (int L = 0; L < 3; ++L)
      for (int qa = 0; qa < 22; qa += 2)
        kpass<<<dim3(4096, 1), blk, 0, stream>>>(F, F, csb, L, qa,
                                                 pmask(qa, L), pmask(qa + 1, L));
    kmerge<<<dim3(16384), blk, 0, stream>>>(park, (unsigned int*)d_out);
  }
}

// Round 17
// 70.948 us; speedup vs baseline: 2.0873x; 1.3716x over previous
//
#include <hip/hip_runtime.h>

// 22-qubit, 3-layer RY variational circuit — forward-frame, window-phase version.
// Real/imag planes evolve independently (all gates real).
//
// Forward frame: state in natural order; CNOT chains folded into masks/signs.
//   L0 q: mask e_q;  L1 q: mask e_q^e_{q+1}, sign parity(p_0..p_q);
//   L2 q: mask e_q^e_{q+2}, sign parity(p_q,p_{q-2},..);  out[l]=buf[sigma^2(l)].
//
// R17: shfl-rots eliminated. Each sweep = 3 phases with a sliding 5-bit
// REGISTER window (32 elems/thread); all gate masks inside the window are pure
// reg-rots (0 DS ops). Windows: sweep1 {0-4},{4-8},{8-12} (+2 mixed rots for
// L2 q3,q7); sweep2 {11-15},{14-18},{17-21} (all pure). DS ops/elem: 27 -> 10.
// All cross-phase reorderings verified via f1(m2)==f2(m1) mod 2. SM sign
// masks = physical-bit sets, unchanged from R16 (passing, absmax 0.031).

#define NQ 22
#define NSTATES (1u << NQ)
#define IDXMASK (NSTATES - 1u)

__device__ __forceinline__ unsigned short f2bf(float x) {
  unsigned int b = __float_as_uint(x);
  b += 0x7FFFu + ((b >> 16) & 1u);   // round-to-nearest-even
  return (unsigned short)(b >> 16);
}
__device__ __forceinline__ float bf2f(unsigned short h) {
  return __uint_as_float((unsigned int)h << 16);
}
// LDS swizzle for 13-bit local index: bank bits 0..4 ^= l5..9 ^ l10..12.
__device__ __forceinline__ unsigned SW(unsigned l) {
  return l ^ ((l >> 5) & 31u) ^ ((l >> 10) & 7u);
}

// Generalized RY butterfly (pair enumeration by LOWEST set bit of MR).
template <int ML, int MR, int RS, unsigned SM, int N>
__device__ __forceinline__ void rot(float (&v)[N], float c, float s, unsigned pbase) {
  int sb = __popc(pbase & SM) & 1;
  float sp = sb ? s : -s;
  constexpr int LB = MR & (-MR);
  if (ML == 0) {
#pragma unroll
    for (int i = 0; i < N; ++i)
      if (!(i & LB)) {
        const int j = i ^ MR;
        const int pi = __builtin_popcount(((unsigned)i << RS) & SM) & 1;
        const int pj = __builtin_popcount(((unsigned)j << RS) & SM) & 1;
        float a = v[i], b = v[j];
        v[i] = fmaf(pi ? -sp : sp, b, c * a);
        v[j] = fmaf(pj ? -sp : sp, a, c * b);
      }
  } else if (MR == 0) {
#pragma unroll
    for (int i = 0; i < N; ++i) {
      float o = __shfl_xor(v[i], ML, 64);
      const int pi = __builtin_popcount(((unsigned)i << RS) & SM) & 1;
      v[i] = fmaf(pi ? -sp : sp, o, c * v[i]);
    }
  } else {
#pragma unroll
    for (int i = 0; i < N; ++i)
      if (!(i & LB)) {
        const int j = i ^ MR;
        float oa = __shfl_xor(v[j], ML, 64);
        float ob = __shfl_xor(v[i], ML, 64);
        const int pi = __builtin_popcount(((unsigned)i << RS) & SM) & 1;
        const int pj = __builtin_popcount(((unsigned)j << RS) & SM) & 1;
        v[i] = fmaf(pi ? -sp : sp, oa, c * v[i]);
        v[j] = fmaf(pj ? -sp : sp, ob, c * v[j]);
      }
  }
}

// setup: input dtype flag + 66 sincos pairs
__global__ void ksetup(const unsigned int* __restrict__ probe,
                       const void* __restrict__ prm,
                       float* __restrict__ csb, int* __restrict__ flagp) {
  __shared__ int anybad;
  if (threadIdx.x == 0) anybad = 0;
  __syncthreads();
  int bad = 0;
  for (int i = threadIdx.x; i < 4096; i += 256) {
    unsigned e = (probe[i] >> 7) & 0xFFu;
    bad |= (e >= 0x90u);
  }
  if (bad) anybad = 1;
  __syncthreads();
  int f = anybad ? 0 : 1;
  if (threadIdx.x == 0) *flagp = f;
  int i = threadIdx.x;
  if (i < 66) {
    float a = f ? bf2f(((const unsigned short*)prm)[i]) : ((const float*)prm)[i];
    float sv, cv;
    sincosf(0.5f * a, &sv, &cv);
    csb[i] = cv; csb[66 + i] = sv;
  }
}

#define RC(k) csb[k], csb[66 + (k)]

// ---- sweep 1: masks within bits 0..12 (36 gates), 3 window phases ----
// 256 threads, 32 elems/thread, tile = 2^13 f32 (32KB LDS), 5 blocks/CU.
// P0: regs=l0..4,  lane=l5..10, wv=l11..12
// P1: regs=l4..8,  lane=l0..3+l9..10, wv=l11..12  (+mixed L2 q3: bit3=lane3)
// P2: regs=l8..12, lane=l0..4+l7, wv=l5..6        (+mixed L2 q7: bit7=lane5)
// Store: W'[cb9=p2..10][B=p13..21][h2=p11..12][e=p0..1] f32.
__global__ void __launch_bounds__(256, 5)
ksweep1(const void* re, const void* im, float* __restrict__ Wr,
        float* __restrict__ Wi, const float* __restrict__ csb,
        const int* __restrict__ flag) {
  __shared__ float ld[8192];
  int tid = threadIdx.x;
  int f = *flag;
  int pl = blockIdx.y;
  const void* src = (pl ^ (f ? 0 : 1)) ? im : re;
  float* W = pl ? Wi : Wr;
  unsigned B = blockIdx.x;
  unsigned tb = B << 13;

  if (f) {
    const unsigned short* sp = (const unsigned short*)src + tb;
#pragma unroll
    for (int k = 0; k < 4; ++k) {
      unsigned C = (unsigned)k * 256 + tid;       // 16B chunk = 8 bf16
      uint4 q = *reinterpret_cast<const uint4*>(sp + C * 8);
      unsigned e0 = C * 8;
      ld[SW(e0 + 0)] = bf2f((unsigned short)(q.x & 0xFFFFu));
      ld[SW(e0 + 1)] = bf2f((unsigned short)(q.x >> 16));
      ld[SW(e0 + 2)] = bf2f((unsigned short)(q.y & 0xFFFFu));
      ld[SW(e0 + 3)] = bf2f((unsigned short)(q.y >> 16));
      ld[SW(e0 + 4)] = bf2f((unsigned short)(q.z & 0xFFFFu));
      ld[SW(e0 + 5)] = bf2f((unsigned short)(q.z >> 16));
      ld[SW(e0 + 6)] = bf2f((unsigned short)(q.w & 0xFFFFu));
      ld[SW(e0 + 7)] = bf2f((unsigned short)(q.w >> 16));
    }
  } else {
    const float* sp = (const float*)src + tb;
#pragma unroll
    for (int k = 0; k < 8; ++k) {
      unsigned C = (unsigned)k * 256 + tid;       // 16B chunk = 4 f32
      float4 t = *reinterpret_cast<const float4*>(sp + C * 4);
      unsigned e0 = C * 4;
      ld[SW(e0 + 0)] = t.x; ld[SW(e0 + 1)] = t.y;
      ld[SW(e0 + 2)] = t.z; ld[SW(e0 + 3)] = t.w;
    }
  }
  __syncthreads();

  int lane = tid & 63, wv = tid >> 6;              // wv 0..3
  float v[32];

  // ---- P0: window {0..4}: L0 q0..4; L1 q0..3; L2 q0..2 ----
  unsigned lb0 = ((unsigned)lane << 5) | ((unsigned)wv << 11);
  unsigned pb0 = tb | lb0;
#pragma unroll
  for (int i = 0; i < 32; ++i) v[i] = ld[SW(lb0 | (unsigned)i)];
  rot<0, 1, 0, 0x1u>(v, RC(0), pb0);
  rot<0, 2, 0, 0x2u>(v, RC(1), pb0);
  rot<0, 4, 0, 0x4u>(v, RC(2), pb0);
  rot<0, 8, 0, 0x8u>(v, RC(3), pb0);
  rot<0, 16, 0, 0x10u>(v, RC(4), pb0);
  rot<0, 3, 0, 0x1u>(v, RC(22), pb0);
  rot<0, 6, 0, 0x3u>(v, RC(23), pb0);
  rot<0, 12, 0, 0x7u>(v, RC(24), pb0);
  rot<0, 24, 0, 0xFu>(v, RC(25), pb0);
  rot<0, 5, 0, 0x1u>(v, RC(44), pb0);
  rot<0, 10, 0, 0x2u>(v, RC(45), pb0);
  rot<0, 20, 0, 0x5u>(v, RC(46), pb0);
#pragma unroll
  for (int i = 0; i < 32; ++i) ld[SW(lb0 | (unsigned)i)] = v[i];
  __syncthreads();

  // ---- P1: window {4..8}: L0 q5..8; L1 q4..7; L2 q3(mixed),q4..6 ----
  unsigned lb1 = ((unsigned)lane & 15u) | ((((unsigned)lane >> 4) & 3u) << 9) |
                 ((unsigned)wv << 11);
  unsigned pb1 = tb | lb1;
#pragma unroll
  for (int i = 0; i < 32; ++i) v[i] = ld[SW(lb1 | ((unsigned)i << 4))];
  rot<0, 2, 4, 0x20u>(v, RC(5), pb1);
  rot<0, 4, 4, 0x40u>(v, RC(6), pb1);
  rot<0, 8, 4, 0x80u>(v, RC(7), pb1);
  rot<0, 16, 4, 0x100u>(v, RC(8), pb1);
  rot<0, 3, 4, 0x1Fu>(v, RC(26), pb1);
  rot<0, 6, 4, 0x3Fu>(v, RC(27), pb1);
  rot<0, 12, 4, 0x7Fu>(v, RC(28), pb1);
  rot<0, 24, 4, 0xFFu>(v, RC(29), pb1);
  rot<8, 2, 4, 0xAu>(v, RC(47), pb1);     // L2 q3: mask (3,5), bit3=lane3
  rot<0, 5, 4, 0x15u>(v, RC(48), pb1);
  rot<0, 10, 4, 0x2Au>(v, RC(49), pb1);
  rot<0, 20, 4, 0x55u>(v, RC(50), pb1);
#pragma unroll
  for (int i = 0; i < 32; ++i) ld[SW(lb1 | ((unsigned)i << 4))] = v[i];
  __syncthreads();

  // ---- P2: window {8..12}: L0 q9..12; L1 q8..11; L2 q7(mixed),q8..10 ----
  unsigned lb2 = ((unsigned)lane & 31u) | ((unsigned)wv << 5) |
                 ((((unsigned)lane >> 5) & 1u) << 7);
  unsigned pb2 = tb | lb2;
#pragma unroll
  for (int i = 0; i < 32; ++i) v[i] = ld[SW(lb2 | ((unsigned)i << 8))];
  rot<0, 2, 8, 0x200u>(v, RC(9), pb2);
  rot<0, 4, 8, 0x400u>(v, RC(10), pb2);
  rot<0, 8, 8, 0x800u>(v, RC(11), pb2);
  rot<0, 16, 8, 0x1000u>(v, RC(12), pb2);
  rot<0, 3, 8, 0x1FFu>(v, RC(30), pb2);
  rot<0, 6, 8, 0x3FFu>(v, RC(31), pb2);
  rot<0, 12, 8, 0x7FFu>(v, RC(32), pb2);
  rot<0, 24, 8, 0xFFFu>(v, RC(33), pb2);
  rot<32, 2, 8, 0xAAu>(v, RC(51), pb2);   // L2 q7: mask (7,9), bit7=lane5
  rot<0, 5, 8, 0x155u>(v, RC(52), pb2);
  rot<0, 10, 8, 0x2AAu>(v, RC(53), pb2);
  rot<0, 20, 8, 0x555u>(v, RC(54), pb2);
#pragma unroll
  for (int i = 0; i < 32; ++i) ld[SW(lb2 | ((unsigned)i << 8))] = v[i];
  __syncthreads();

  // ---- store to W' [cb9<<13 | B<<4 | h2<<2 | e] ----
#pragma unroll
  for (int k = 0; k < 8; ++k) {
    unsigned c = (unsigned)k * 256 + tid;   // 0..2047
    unsigned cb9 = c >> 2, h2 = c & 3;
    unsigned lloc = (cb9 << 2) | (h2 << 11);
    float4 t;
    t.x = ld[SW(lloc | 0)];
    t.y = ld[SW(lloc | 1)];
    t.z = ld[SW(lloc | 2)];
    t.w = ld[SW(lloc | 3)];
    *reinterpret_cast<float4*>(W + (((size_t)cb9 << 13) | ((size_t)B << 4) |
                                    (h2 << 2))) = t;
  }
}

// ---- sweep 2: masks within bits 11..21 (30 gates), 3 window phases ----
// 512 threads (both planes: waves 0-3 re / 4-7 im), 2x32KB LDS, cb = p2..10.
// Local (per plane): l0,l1 = p0,p1; l2..12 = p11..21 (hh).
// Q0: regs=l2..6  (p11..15), lane=l0,1,7..10, wq=l11,12
// Q1: regs=l5..9  (p14..18), lane=l0..4,l10,  wq=l11,12
// Q2: regs=l8..12 (p17..21), lane=l0..5,      wq=l6,7
__global__ void __launch_bounds__(512, 4)
ksweep2(const float* __restrict__ Wr, const float* __restrict__ Wi,
        unsigned* __restrict__ tmp, const float* __restrict__ csb) {
  __shared__ float ld[2][8192];
  int tid = threadIdx.x;
  unsigned cb = blockIdx.x;             // p2..10

#pragma unroll
  for (int k = 0; k < 8; ++k) {
    unsigned C = (unsigned)k * 512 + tid;   // 0..4095
    int p = C >> 11;
    unsigned hh = C & 2047u;
    const float* W = p ? Wi : Wr;
    float4 t = *reinterpret_cast<const float4*>(W + (((size_t)cb << 13) |
                                                     (hh << 2)));
    unsigned e0 = hh << 2;
    ld[p][SW(e0 + 0)] = t.x; ld[p][SW(e0 + 1)] = t.y;
    ld[p][SW(e0 + 2)] = t.z; ld[p][SW(e0 + 3)] = t.w;
  }
  __syncthreads();

  int lane = tid & 63;
  int wq = (tid >> 6) & 3;
  int pl = tid >> 8;                    // plane
  float* L = ld[pl];
  float v[32];

  // ---- Q0: phys {11..15}: L0 q13..15; L1 q12..14; L2 q11..13 ----
  unsigned lbQ0 = ((unsigned)lane & 3u) | ((((unsigned)lane >> 2) & 15u) << 7) |
                  ((unsigned)wq << 11);
  unsigned pb0 = ((unsigned)lane & 3u) | (cb << 2) |
                 ((((unsigned)lane >> 2) & 15u) << 16) | ((unsigned)wq << 20);
#pragma unroll
  for (int i = 0; i < 32; ++i) v[i] = L[SW(lbQ0 | ((unsigned)i << 2))];
  rot<0, 4, 11, (1u << 13)>(v, RC(13), pb0);
  rot<0, 8, 11, (1u << 14)>(v, RC(14), pb0);
  rot<0, 16, 11, (1u << 15)>(v, RC(15), pb0);
  rot<0, 6, 11, 0x1FFFu>(v, RC(34), pb0);
  rot<0, 12, 11, 0x3FFFu>(v, RC(35), pb0);
  rot<0, 24, 11, 0x7FFFu>(v, RC(36), pb0);
  rot<0, 5, 11, 0xAAAu>(v, RC(55), pb0);
  rot<0, 10, 11, 0x1555u>(v, RC(56), pb0);
  rot<0, 20, 11, 0x2AAAu>(v, RC(57), pb0);
#pragma unroll
  for (int i = 0; i < 32; ++i) L[SW(lbQ0 | ((unsigned)i << 2))] = v[i];
  __syncthreads();

  // ---- Q1: phys {14..18}: L0 q16..18; L1 q15..17; L2 q14..16 ----
  unsigned lbQ1 = ((unsigned)lane & 31u) | ((((unsigned)lane >> 5) & 1u) << 10) |
                  ((unsigned)wq << 11);
  unsigned pb1 = ((unsigned)lane & 3u) | (cb << 2) |
                 ((((unsigned)lane >> 2) & 7u) << 11) |
                 ((((unsigned)lane >> 5) & 1u) << 19) | ((unsigned)wq << 20);
#pragma unroll
  for (int i = 0; i < 32; ++i) v[i] = L[SW(lbQ1 | ((unsigned)i << 5))];
  rot<0, 4, 14, (1u << 16)>(v, RC(16), pb1);
  rot<0, 8, 14, (1u << 17)>(v, RC(17), pb1);
  rot<0, 16, 14, (1u << 18)>(v, RC(18), pb1);
  rot<0, 6, 14, 0xFFFFu>(v, RC(37), pb1);
  rot<0, 12, 14, 0x1FFFFu>(v, RC(38), pb1);
  rot<0, 24, 14, 0x3FFFFu>(v, RC(39), pb1);
  rot<0, 5, 14, 0x5555u>(v, RC(58), pb1);
  rot<0, 10, 14, 0xAAAAu>(v, RC(59), pb1);
  rot<0, 20, 14, 0x15555u>(v, RC(60), pb1);
#pragma unroll
  for (int i = 0; i < 32; ++i) L[SW(lbQ1 | ((unsigned)i << 5))] = v[i];
  __syncthreads();

  // ---- Q2: phys {17..21}: L0 q19..21; L1 q18..21; L2 q17..21 ----
  unsigned lbQ2 = ((unsigned)lane & 63u) | ((unsigned)wq << 6);
  unsigned pb2 = ((unsigned)lane & 3u) | (cb << 2) |
                 ((((unsigned)lane >> 2) & 15u) << 11) | ((unsigned)wq << 15);
#pragma unroll
  for (int i = 0; i < 32; ++i) v[i] = L[SW(lbQ2 | ((unsigned)i << 8))];
  rot<0, 4, 17, (1u << 19)>(v, RC(19), pb2);
  rot<0, 8, 17, (1u << 20)>(v, RC(20), pb2);
  rot<0, 16, 17, (1u << 21)>(v, RC(21), pb2);
  rot<0, 6, 17, 0x7FFFFu>(v, RC(40), pb2);
  rot<0, 12, 17, 0xFFFFFu>(v, RC(41), pb2);
  rot<0, 24, 17, 0x1FFFFFu>(v, RC(42), pb2);
  rot<0, 16, 17, 0x3FFFFFu>(v, RC(43), pb2);
  rot<0, 5, 17, 0x2AAAAu>(v, RC(61), pb2);
  rot<0, 10, 17, 0x55555u>(v, RC(62), pb2);
  rot<0, 20, 17, 0xAAAAAu>(v, RC(63), pb2);
  rot<0, 8, 17, 0x155555u>(v, RC(64), pb2);
  rot<0, 16, 17, 0x2AAAAAu>(v, RC(65), pb2);
#pragma unroll
  for (int i = 0; i < 32; ++i) L[SW(lbQ2 | ((unsigned)i << 8))] = v[i];
  __syncthreads();

  // pack both planes -> p-linear u32 tmp: p = e | cb<<2 | hh<<11
#pragma unroll
  for (int k = 0; k < 4; ++k) {
    unsigned Q = (unsigned)k * 512 + tid;   // hh
    unsigned e0 = Q << 2;
    uint4 o;
    o.x = (unsigned)f2bf(ld[0][SW(e0 + 0)]) | ((unsigned)f2bf(ld[1][SW(e0 + 0)]) << 16);
    o.y = (unsigned)f2bf(ld[0][SW(e0 + 1)]) | ((unsigned)f2bf(ld[1][SW(e0 + 1)]) << 16);
    o.z = (unsigned)f2bf(ld[0][SW(e0 + 2)]) | ((unsigned)f2bf(ld[1][SW(e0 + 2)]) << 16);
    o.w = (unsigned)f2bf(ld[0][SW(e0 + 3)]) | ((unsigned)f2bf(ld[1][SW(e0 + 3)]) << 16);
    *reinterpret_cast<uint4*>(tmp + (((size_t)Q << 11) | (cb << 2))) = o;
  }
}

// ---- final gather: out[l] = tmp[sigma^2(l)] (R13-proven) ----
__global__ void __launch_bounds__(256)
kfinal(const unsigned* __restrict__ tmp, unsigned* __restrict__ out32) {
  unsigned T = blockIdx.x * 256 + threadIdx.x;   // quad id [0, 2^20)
  unsigned lb = T << 2;
  unsigned s = (lb ^ (lb << 2)) & IDXMASK;       // %4 == 0
  const uint4* w = reinterpret_cast<const uint4*>(tmp + (s & ~15u));
  uint4 a = w[0], b = w[1], c = w[2], d = w[3];
  uint4 o;
  switch ((s >> 2) & 3u) {
    case 0: o = make_uint4(a.x, b.y, c.z, d.w); break;   // 0,5,10,15
    case 1: o = make_uint4(b.x, a.y, d.z, c.w); break;   // 4,1,14,11
    case 2: o = make_uint4(c.x, d.y, a.z, b.w); break;   // 8,13,2,7
    default: o = make_uint4(d.x, c.y, b.z, a.w); break;  // 12,9,6,3
  }
  *reinterpret_cast<uint4*>(out32 + lb) = o;
}

// ---------------- proven tier-C fallback (R6) ----------------
__global__ void __launch_bounds__(256)
kinit(const void* s0, const void* s1, float* d0, float* d1,
      const int* __restrict__ flag, int basepl) {
  int pl = blockIdx.y + basepl;
  int f = *flag;
  const void* src = (pl ^ (f ? 0 : 1)) ? s1 : s0;
  float* dst = pl ? d1 : d0;
  unsigned p = blockIdx.x * 256 + threadIdx.x;
  unsigned q = (p ^ (p << 2)) & IDXMASK;
  dst[p] = f ? bf2f(((const unsigned short*)src)[q]) : ((const float*)src)[q];
}
__global__ void __launch_bounds__(256)
kpass(float* b0, float* b1, const float* __restrict__ csb,
      int L, int qa, unsigned ma, unsigned mb) {
  int k = L * 22 + qa;
  float ca = csb[k], sa = csb[66 + k];
  float cb = csb[k + 1], sb = csb[66 + k + 1];
  float* buf = blockIdx.y ? b1 : b0;
  unsigned t = blockIdx.x * 256 + threadIdx.x;
  unsigned j = (t & ((1u << qa) - 1u)) | ((t >> qa) << (qa + 2));
  unsigned p = j;
  if (L == 0)      { p ^= p << 2; p ^= p << 4; p ^= p << 8; p ^= p << 16; }
  else if (L == 1) { p ^= p << 1; p ^= p << 2; p ^= p << 4; p ^= p << 8; p ^= p << 16; }
  p &= IDXMASK;
  unsigned mc = ma ^ mb;
  float x0 = buf[p], x1 = buf[p ^ ma], x2 = buf[p ^ mb], x3 = buf[p ^ mc];
  float y0 = ca * x0 - sa * x1, y1 = sa * x0 + ca * x1;
  float y2 = ca * x2 - sa * x3, y3 = sa * x2 + ca * x3;
  buf[p]      = cb * y0 - sb * y2;
  buf[p ^ ma] = cb * y1 - sb * y3;
  buf[p ^ mb] = sb * y0 + cb * y2;
  buf[p ^ mc] = sb * y1 + cb * y3;
}
__global__ void __launch_bounds__(256)
kpark(const float* __restrict__ fv, unsigned short* __restrict__ park) {
  unsigned j = blockIdx.x * 256 + threadIdx.x;
  park[j] = f2bf(fv[j]);
}
__global__ void __launch_bounds__(256)
kmerge(const unsigned short* __restrict__ park, unsigned int* outw) {
  unsigned j = blockIdx.x * 256 + threadIdx.x;
  float vv = __uint_as_float(outw[j]);
  outw[j] = (unsigned)park[j] | ((unsigned)f2bf(vv) << 16);
}
static inline unsigned pmask(int q, int L) {
  unsigned r = 0;
  if (L == 0)      for (unsigned m = 1u << q; m < NSTATES; m <<= 2) r ^= m;
  else if (L == 1) for (unsigned m = 1u << q; m < NSTATES; m <<= 1) r ^= m;
  else r = 1u << q;
  return r;
}

extern "C" void kernel_launch(void* const* d_in, const int* in_sizes, int n_in,
                              void* d_out, int out_size, void* d_ws, size_t ws_size,
                              hipStream_t stream) {
  (void)out_size;
  const void* prm = d_in[0];
  const void* re  = d_in[1];
  const void* im  = d_in[2];
  if (in_sizes[0] != 66) {   // defensive size-based remap
    const void* big[2] = {nullptr, nullptr};
    int nb = 0;
    for (int i = 0; i < n_in; ++i) {
      if (in_sizes[i] == 66) prm = d_in[i];
      else if (nb < 2) big[nb++] = d_in[i];
    }
    if (nb == 2) { re = big[0]; im = big[1]; }
  }
  const size_t N = NSTATES;

  if (ws_size >= N * 12 + 1024) {
    // ---- fast path: 2 window-phase sweeps + gather ----
    float* Wr = (float*)d_ws;
    float* Wi = Wr + N;
    unsigned* tmp = (unsigned*)(Wi + N);
    float* csb = (float*)(tmp + N);
    int* flag = (int*)(csb + 140);
    ksetup<<<1, 256, 0, stream>>>((const unsigned int*)re, prm, csb, flag);
    ksweep1<<<dim3(512, 2), 256, 0, stream>>>(re, im, Wr, Wi, csb, flag);
    ksweep2<<<dim3(512), 512, 0, stream>>>(Wr, Wi, tmp, csb);
    kfinal<<<dim3(4096), 256, 0, stream>>>(tmp, (unsigned*)d_out);
  } else {
    // ---- tier C (proven R6): d_out as f32 buffer; ~8.4MB ws ----
    float* F = (float*)d_out;
    unsigned short* park = (unsigned short*)d_ws;
    float* csb = (float*)((char*)d_ws + N * 2);
    int* flag = (int*)(csb + 140);
    dim3 blk(256);
    ksetup<<<1, 256, 0, stream>>>((const unsigned int*)re, prm, csb, flag);
    kinit<<<dim3(16384, 1), blk, 0, stream>>>(re, im, F, F, flag, 0);
    for (int L = 0; L < 3; ++L)
      for (int qa = 0; qa < 22; qa += 2)
        kpass<<<dim3(4096, 1), blk, 0, stream>>>(F, F, csb, L, qa,
                                                 pmask(qa, L), pmask(qa + 1, L));
    kpark<<<dim3(16384), blk, 0, stream>>>(F, park);
    kinit<<<dim3(16384, 1), blk, 0, stream>>>(re, im, F, F, flag, 1);
    for (int L = 0; L < 3; ++L)
      for (int qa = 0; qa < 22; qa += 2)
        kpass<<<dim3(4096, 1), blk, 0, stream>>>(F, F, csb, L, qa,
                                                 pmask(qa, L), pmask(qa + 1, L));
    kmerge<<<dim3(16384), blk, 0, stream>>>(park, (unsigned int*)d_out);
  }
}

// Round 19
// 64.227 us; speedup vs baseline: 2.3057x; 1.1046x over previous
//
#include <hip/hip_runtime.h>

// 22-qubit, 3-layer RY variational circuit — forward-frame, window-phase version.
// Real/imag planes evolve independently (all gates real).
//
// Forward frame: state in natural order; CNOT chains folded into masks/signs.
//   L0 q: mask e_q;  L1 q: mask e_q^e_{q+1}, sign parity(p_0..p_q);
//   L2 q: mask e_q^e_{q+2}, sign parity(p_q,p_{q-2},..);  out[l]=buf[sigma^2(l)].
//
// R19 = R18 with the ksweep1 packed-store loop bound fixed (k<2 -> k<4; the
// block owns 8192 packed u32 = 2048 uint4 chunks; R18 wrote only half, leaving
// p10=1 entries as ws poison -> absmax 5.375-eps signature).
// Design (from R18): W' = u32-packed (re|im) bf16; both planes per block in
// both sweeps; setup folded in-block; sweep1 P0 loads global->regs directly.
// Rot schedules identical to R17 (passing, absmax 0.031).

#define NQ 22
#define NSTATES (1u << NQ)
#define IDXMASK (NSTATES - 1u)

__device__ __forceinline__ unsigned short f2bf(float x) {
  unsigned int b = __float_as_uint(x);
  b += 0x7FFFu + ((b >> 16) & 1u);   // round-to-nearest-even
  return (unsigned short)(b >> 16);
}
__device__ __forceinline__ float bf2f(unsigned short h) {
  return __uint_as_float((unsigned int)h << 16);
}
// LDS swizzle for 13-bit local index: bank bits 0..4 ^= l5..9 ^ l10..12.
__device__ __forceinline__ unsigned SW(unsigned l) {
  return l ^ ((l >> 5) & 31u) ^ ((l >> 10) & 7u);
}

// Generalized RY butterfly (pair enumeration by LOWEST set bit of MR).
template <int ML, int MR, int RS, unsigned SM, int N>
__device__ __forceinline__ void rot(float (&v)[N], float c, float s, unsigned pbase) {
  int sb = __popc(pbase & SM) & 1;
  float sp = sb ? s : -s;
  constexpr int LB = MR & (-MR);
  if (ML == 0) {
#pragma unroll
    for (int i = 0; i < N; ++i)
      if (!(i & LB)) {
        const int j = i ^ MR;
        const int pi = __builtin_popcount(((unsigned)i << RS) & SM) & 1;
        const int pj = __builtin_popcount(((unsigned)j << RS) & SM) & 1;
        float a = v[i], b = v[j];
        v[i] = fmaf(pi ? -sp : sp, b, c * a);
        v[j] = fmaf(pj ? -sp : sp, a, c * b);
      }
  } else if (MR == 0) {
#pragma unroll
    for (int i = 0; i < N; ++i) {
      float o = __shfl_xor(v[i], ML, 64);
      const int pi = __builtin_popcount(((unsigned)i << RS) & SM) & 1;
      v[i] = fmaf(pi ? -sp : sp, o, c * v[i]);
    }
  } else {
#pragma unroll
    for (int i = 0; i < N; ++i)
      if (!(i & LB)) {
        const int j = i ^ MR;
        float oa = __shfl_xor(v[j], ML, 64);
        float ob = __shfl_xor(v[i], ML, 64);
        const int pi = __builtin_popcount(((unsigned)i << RS) & SM) & 1;
        const int pj = __builtin_popcount(((unsigned)j << RS) & SM) & 1;
        v[i] = fmaf(pi ? -sp : sp, oa, c * v[i]);
        v[j] = fmaf(pj ? -sp : sp, ob, c * v[j]);
      }
  }
}

// in-block setup: flag from probe words + 66 sincos pairs into LDS
__device__ __forceinline__ int blk_setup(const void* re, const void* prm,
                                         float* cs2, int tid) {
  int bad = 0;
  const unsigned* pr = (const unsigned*)re;
#pragma unroll
  for (int i = 0; i < 64; ++i) bad |= (((pr[i] >> 7) & 0xFFu) >= 0x90u);
  int f = bad ? 0 : 1;
  if (tid < 66) {
    float a = f ? bf2f(((const unsigned short*)prm)[tid])
                : ((const float*)prm)[tid];
    float sv, cv;
    sincosf(0.5f * a, &sv, &cv);
    cs2[tid] = cv; cs2[66 + tid] = sv;
  }
  __syncthreads();
  return f;
}

#define RC(k) csb[k], csb[66 + (k)]

// ---- sweep 1: masks within bits 0..12 (36 gates), 3 window phases ----
// 512 threads: waves 0-3 plane-re, 4-7 plane-im; 2 x 32KB LDS; B = p13..21.
// Per half (256 thr): P0 regs=l0..4 (direct global load, 32 consec elems);
// P1 regs=l4..8 (+mixed L2 q3); P2 regs=l8..12 (+mixed L2 q7).
// Store: packed u32 (re|im) to W[cb9<<13 | B<<4 | h2<<2 | e].
__global__ void __launch_bounds__(512, 4)
ksweep1(const void* re, const void* im, unsigned* __restrict__ W,
        const void* prm) {
  __shared__ float ld[2][8192];
  __shared__ float cs2[132];
  int tid = threadIdx.x;
  int f = blk_setup(re, prm, cs2, tid);
  const float* csb = cs2;

  int pl = tid >> 8;
  int htid = tid & 255;
  int lane = htid & 63, wv = htid >> 6;          // wv 0..3
  const void* src = (pl ^ (f ? 0 : 1)) ? im : re;
  float* L = ld[pl];
  unsigned B = blockIdx.x;
  unsigned tb = B << 13;
  float v[32];

  // ---- P0: window {0..4}: direct load of 32 consecutive elems ----
  unsigned lb0 = ((unsigned)lane << 5) | ((unsigned)wv << 11);
  unsigned pb0 = tb | lb0;
  if (f) {
    const unsigned short* sp = (const unsigned short*)src + tb + lb0;
#pragma unroll
    for (int j = 0; j < 4; ++j) {
      uint4 q = *reinterpret_cast<const uint4*>(sp + j * 8);
      v[j*8+0]=bf2f((unsigned short)(q.x & 0xFFFFu));
      v[j*8+1]=bf2f((unsigned short)(q.x >> 16));
      v[j*8+2]=bf2f((unsigned short)(q.y & 0xFFFFu));
      v[j*8+3]=bf2f((unsigned short)(q.y >> 16));
      v[j*8+4]=bf2f((unsigned short)(q.z & 0xFFFFu));
      v[j*8+5]=bf2f((unsigned short)(q.z >> 16));
      v[j*8+6]=bf2f((unsigned short)(q.w & 0xFFFFu));
      v[j*8+7]=bf2f((unsigned short)(q.w >> 16));
    }
  } else {
    const float* sp = (const float*)src + tb + lb0;
#pragma unroll
    for (int j = 0; j < 8; ++j) {
      float4 t = *reinterpret_cast<const float4*>(sp + j * 4);
      v[j*4+0]=t.x; v[j*4+1]=t.y; v[j*4+2]=t.z; v[j*4+3]=t.w;
    }
  }
  rot<0, 1, 0, 0x1u>(v, RC(0), pb0);
  rot<0, 2, 0, 0x2u>(v, RC(1), pb0);
  rot<0, 4, 0, 0x4u>(v, RC(2), pb0);
  rot<0, 8, 0, 0x8u>(v, RC(3), pb0);
  rot<0, 16, 0, 0x10u>(v, RC(4), pb0);
  rot<0, 3, 0, 0x1u>(v, RC(22), pb0);
  rot<0, 6, 0, 0x3u>(v, RC(23), pb0);
  rot<0, 12, 0, 0x7u>(v, RC(24), pb0);
  rot<0, 24, 0, 0xFu>(v, RC(25), pb0);
  rot<0, 5, 0, 0x1u>(v, RC(44), pb0);
  rot<0, 10, 0, 0x2u>(v, RC(45), pb0);
  rot<0, 20, 0, 0x5u>(v, RC(46), pb0);
#pragma unroll
  for (int i = 0; i < 32; ++i) L[SW(lb0 | (unsigned)i)] = v[i];
  __syncthreads();

  // ---- P1: window {4..8}: L0 q5..8; L1 q4..7; L2 q3(mixed),q4..6 ----
  unsigned lb1 = ((unsigned)lane & 15u) | ((((unsigned)lane >> 4) & 3u) << 9) |
                 ((unsigned)wv << 11);
  unsigned pb1 = tb | lb1;
#pragma unroll
  for (int i = 0; i < 32; ++i) v[i] = L[SW(lb1 | ((unsigned)i << 4))];
  rot<0, 2, 4, 0x20u>(v, RC(5), pb1);
  rot<0, 4, 4, 0x40u>(v, RC(6), pb1);
  rot<0, 8, 4, 0x80u>(v, RC(7), pb1);
  rot<0, 16, 4, 0x100u>(v, RC(8), pb1);
  rot<0, 3, 4, 0x1Fu>(v, RC(26), pb1);
  rot<0, 6, 4, 0x3Fu>(v, RC(27), pb1);
  rot<0, 12, 4, 0x7Fu>(v, RC(28), pb1);
  rot<0, 24, 4, 0xFFu>(v, RC(29), pb1);
  rot<8, 2, 4, 0xAu>(v, RC(47), pb1);     // L2 q3: mask (3,5), bit3=lane3
  rot<0, 5, 4, 0x15u>(v, RC(48), pb1);
  rot<0, 10, 4, 0x2Au>(v, RC(49), pb1);
  rot<0, 20, 4, 0x55u>(v, RC(50), pb1);
#pragma unroll
  for (int i = 0; i < 32; ++i) L[SW(lb1 | ((unsigned)i << 4))] = v[i];
  __syncthreads();

  // ---- P2: window {8..12}: L0 q9..12; L1 q8..11; L2 q7(mixed),q8..10 ----
  unsigned lb2 = ((unsigned)lane & 31u) | ((unsigned)wv << 5) |
                 ((((unsigned)lane >> 5) & 1u) << 7);
  unsigned pb2 = tb | lb2;
#pragma unroll
  for (int i = 0; i < 32; ++i) v[i] = L[SW(lb2 | ((unsigned)i << 8))];
  rot<0, 2, 8, 0x200u>(v, RC(9), pb2);
  rot<0, 4, 8, 0x400u>(v, RC(10), pb2);
  rot<0, 8, 8, 0x800u>(v, RC(11), pb2);
  rot<0, 16, 8, 0x1000u>(v, RC(12), pb2);
  rot<0, 3, 8, 0x1FFu>(v, RC(30), pb2);
  rot<0, 6, 8, 0x3FFu>(v, RC(31), pb2);
  rot<0, 12, 8, 0x7FFu>(v, RC(32), pb2);
  rot<0, 24, 8, 0xFFFu>(v, RC(33), pb2);
  rot<32, 2, 8, 0xAAu>(v, RC(51), pb2);   // L2 q7: mask (7,9), bit7=lane5
  rot<0, 5, 8, 0x155u>(v, RC(52), pb2);
  rot<0, 10, 8, 0x2AAu>(v, RC(53), pb2);
  rot<0, 20, 8, 0x555u>(v, RC(54), pb2);
#pragma unroll
  for (int i = 0; i < 32; ++i) L[SW(lb2 | ((unsigned)i << 8))] = v[i];
  __syncthreads();

  // ---- packed store: W[cb9<<13 | B<<4 | h2<<2 | e] = re | im<<16 ----
  // Block owns 8192 u32 = 2048 uint4 chunks -> k < 4 with 512 threads.
#pragma unroll
  for (int k = 0; k < 4; ++k) {
    unsigned t = (unsigned)k * 512 + tid;   // 0..2047 chunk id
    unsigned cb9 = t >> 2, h2 = t & 3;      // cb9 0..511, h2 0..3
    unsigned lloc = (cb9 << 2) | (h2 << 11);
    uint4 o;
    o.x = (unsigned)f2bf(ld[0][SW(lloc | 0)]) | ((unsigned)f2bf(ld[1][SW(lloc | 0)]) << 16);
    o.y = (unsigned)f2bf(ld[0][SW(lloc | 1)]) | ((unsigned)f2bf(ld[1][SW(lloc | 1)]) << 16);
    o.z = (unsigned)f2bf(ld[0][SW(lloc | 2)]) | ((unsigned)f2bf(ld[1][SW(lloc | 2)]) << 16);
    o.w = (unsigned)f2bf(ld[0][SW(lloc | 3)]) | ((unsigned)f2bf(ld[1][SW(lloc | 3)]) << 16);
    *reinterpret_cast<uint4*>(W + ((((cb9 << 11) | (B << 2) | h2) << 2))) = o;
  }
}

// ---- sweep 2: masks within bits 11..21 (30 gates), 3 window phases ----
// 512 threads (waves 0-3 re / 4-7 im), 2x32KB LDS, cb = p2..10.
// Stage: CONTIGUOUS 32KB u32 slab W + cb<<13 (in-slab offset o == local l).
__global__ void __launch_bounds__(512, 4)
ksweep2(const unsigned* __restrict__ W, unsigned* __restrict__ tmp,
        const void* re, const void* prm) {
  __shared__ float ld[2][8192];
  __shared__ float cs2[132];
  int tid = threadIdx.x;
  (void)blk_setup(re, prm, cs2, tid);
  const float* csb = cs2;
  unsigned cb = blockIdx.x;             // p2..10

#pragma unroll
  for (int k = 0; k < 4; ++k) {
    unsigned C = (unsigned)k * 512 + tid;   // 0..2047 chunks of 4 u32
    uint4 q = *reinterpret_cast<const uint4*>(W + (cb << 13) + C * 4);
    unsigned o0 = C * 4;
    ld[0][SW(o0 + 0)] = bf2f((unsigned short)(q.x & 0xFFFFu));
    ld[1][SW(o0 + 0)] = bf2f((unsigned short)(q.x >> 16));
    ld[0][SW(o0 + 1)] = bf2f((unsigned short)(q.y & 0xFFFFu));
    ld[1][SW(o0 + 1)] = bf2f((unsigned short)(q.y >> 16));
    ld[0][SW(o0 + 2)] = bf2f((unsigned short)(q.z & 0xFFFFu));
    ld[1][SW(o0 + 2)] = bf2f((unsigned short)(q.z >> 16));
    ld[0][SW(o0 + 3)] = bf2f((unsigned short)(q.w & 0xFFFFu));
    ld[1][SW(o0 + 3)] = bf2f((unsigned short)(q.w >> 16));
  }
  __syncthreads();

  int lane = tid & 63;
  int wq = (tid >> 6) & 3;
  int pl = tid >> 8;                    // plane
  float* L = ld[pl];
  float v[32];

  // ---- Q0: phys {11..15}: L0 q13..15; L1 q12..14; L2 q11..13 ----
  unsigned lbQ0 = ((unsigned)lane & 3u) | ((((unsigned)lane >> 2) & 15u) << 7) |
                  ((unsigned)wq << 11);
  unsigned pb0 = ((unsigned)lane & 3u) | (cb << 2) |
                 ((((unsigned)lane >> 2) & 15u) << 16) | ((unsigned)wq << 20);
#pragma unroll
  for (int i = 0; i < 32; ++i) v[i] = L[SW(lbQ0 | ((unsigned)i << 2))];
  rot<0, 4, 11, (1u << 13)>(v, RC(13), pb0);
  rot<0, 8, 11, (1u << 14)>(v, RC(14), pb0);
  rot<0, 16, 11, (1u << 15)>(v, RC(15), pb0);
  rot<0, 6, 11, 0x1FFFu>(v, RC(34), pb0);
  rot<0, 12, 11, 0x3FFFu>(v, RC(35), pb0);
  rot<0, 24, 11, 0x7FFFu>(v, RC(36), pb0);
  rot<0, 5, 11, 0xAAAu>(v, RC(55), pb0);
  rot<0, 10, 11, 0x1555u>(v, RC(56), pb0);
  rot<0, 20, 11, 0x2AAAu>(v, RC(57), pb0);
#pragma unroll
  for (int i = 0; i < 32; ++i) L[SW(lbQ0 | ((unsigned)i << 2))] = v[i];
  __syncthreads();

  // ---- Q1: phys {14..18}: L0 q16..18; L1 q15..17; L2 q14..16 ----
  unsigned lbQ1 = ((unsigned)lane & 31u) | ((((unsigned)lane >> 5) & 1u) << 10) |
                  ((unsigned)wq << 11);
  unsigned pb1 = ((unsigned)lane & 3u) | (cb << 2) |
                 ((((unsigned)lane >> 2) & 7u) << 11) |
                 ((((unsigned)lane >> 5) & 1u) << 19) | ((unsigned)wq << 20);
#pragma unroll
  for (int i = 0; i < 32; ++i) v[i] = L[SW(lbQ1 | ((unsigned)i << 5))];
  rot<0, 4, 14, (1u << 16)>(v, RC(16), pb1);
  rot<0, 8, 14, (1u << 17)>(v, RC(17), pb1);
  rot<0, 16, 14, (1u << 18)>(v, RC(18), pb1);
  rot<0, 6, 14, 0xFFFFu>(v, RC(37), pb1);
  rot<0, 12, 14, 0x1FFFFu>(v, RC(38), pb1);
  rot<0, 24, 14, 0x3FFFFu>(v, RC(39), pb1);
  rot<0, 5, 14, 0x5555u>(v, RC(58), pb1);
  rot<0, 10, 14, 0xAAAAu>(v, RC(59), pb1);
  rot<0, 20, 14, 0x15555u>(v, RC(60), pb1);
#pragma unroll
  for (int i = 0; i < 32; ++i) L[SW(lbQ1 | ((unsigned)i << 5))] = v[i];
  __syncthreads();

  // ---- Q2: phys {17..21}: L0 q19..21; L1 q18..21; L2 q17..21 ----
  unsigned lbQ2 = ((unsigned)lane & 63u) | ((unsigned)wq << 6);
  unsigned pb2 = ((unsigned)lane & 3u) | (cb << 2) |
                 ((((unsigned)lane >> 2) & 15u) << 11) | ((unsigned)wq << 15);
#pragma unroll
  for (int i = 0; i < 32; ++i) v[i] = L[SW(lbQ2 | ((unsigned)i << 8))];
  rot<0, 4, 17, (1u << 19)>(v, RC(19), pb2);
  rot<0, 8, 17, (1u << 20)>(v, RC(20), pb2);
  rot<0, 16, 17, (1u << 21)>(v, RC(21), pb2);
  rot<0, 6, 17, 0x7FFFFu>(v, RC(40), pb2);
  rot<0, 12, 17, 0xFFFFFu>(v, RC(41), pb2);
  rot<0, 24, 17, 0x1FFFFFu>(v, RC(42), pb2);
  rot<0, 16, 17, 0x3FFFFFu>(v, RC(43), pb2);
  rot<0, 5, 17, 0x2AAAAu>(v, RC(61), pb2);
  rot<0, 10, 17, 0x55555u>(v, RC(62), pb2);
  rot<0, 20, 17, 0xAAAAAu>(v, RC(63), pb2);
  rot<0, 8, 17, 0x155555u>(v, RC(64), pb2);
  rot<0, 16, 17, 0x2AAAAAu>(v, RC(65), pb2);
#pragma unroll
  for (int i = 0; i < 32; ++i) L[SW(lbQ2 | ((unsigned)i << 8))] = v[i];
  __syncthreads();

  // pack both planes -> p-linear u32 tmp: p = e | cb<<2 | hh<<11
#pragma unroll
  for (int k = 0; k < 4; ++k) {
    unsigned Q = (unsigned)k * 512 + tid;   // hh
    unsigned e0 = Q << 2;
    uint4 o;
    o.x = (unsigned)f2bf(ld[0][SW(e0 + 0)]) | ((unsigned)f2bf(ld[1][SW(e0 + 0)]) << 16);
    o.y = (unsigned)f2bf(ld[0][SW(e0 + 1)]) | ((unsigned)f2bf(ld[1][SW(e0 + 1)]) << 16);
    o.z = (unsigned)f2bf(ld[0][SW(e0 + 2)]) | ((unsigned)f2bf(ld[1][SW(e0 + 2)]) << 16);
    o.w = (unsigned)f2bf(ld[0][SW(e0 + 3)]) | ((unsigned)f2bf(ld[1][SW(e0 + 3)]) << 16);
    *reinterpret_cast<uint4*>(tmp + (((size_t)Q << 11) | (cb << 2))) = o;
  }
}

// ---- final gather: out[l] = tmp[sigma^2(l)] (R13-proven) ----
__global__ void __launch_bounds__(256)
kfinal(const unsigned* __restrict__ tmp, unsigned* __restrict__ out32) {
  unsigned T = blockIdx.x * 256 + threadIdx.x;   // quad id [0, 2^20)
  unsigned lb = T << 2;
  unsigned s = (lb ^ (lb << 2)) & IDXMASK;       // %4 == 0
  const uint4* w = reinterpret_cast<const uint4*>(tmp + (s & ~15u));
  uint4 a = w[0], b = w[1], c = w[2], d = w[3];
  uint4 o;
  switch ((s >> 2) & 3u) {
    case 0: o = make_uint4(a.x, b.y, c.z, d.w); break;   // 0,5,10,15
    case 1: o = make_uint4(b.x, a.y, d.z, c.w); break;   // 4,1,14,11
    case 2: o = make_uint4(c.x, d.y, a.z, b.w); break;   // 8,13,2,7
    default: o = make_uint4(d.x, c.y, b.z, a.w); break;  // 12,9,6,3
  }
  *reinterpret_cast<uint4*>(out32 + lb) = o;
}

// ---------------- proven tier-C fallback (R6) ----------------
__global__ void ksetup(const unsigned int* __restrict__ probe,
                       const void* __restrict__ prm,
                       float* __restrict__ csb, int* __restrict__ flagp) {
  __shared__ int anybad;
  if (threadIdx.x == 0) anybad = 0;
  __syncthreads();
  int bad = 0;
  for (int i = threadIdx.x; i < 4096; i += 256) {
    unsigned e = (probe[i] >> 7) & 0xFFu;
    bad |= (e >= 0x90u);
  }
  if (bad) anybad = 1;
  __syncthreads();
  int f = anybad ? 0 : 1;
  if (threadIdx.x == 0) *flagp = f;
  int i = threadIdx.x;
  if (i < 66) {
    float a = f ? bf2f(((const unsigned short*)prm)[i]) : ((const float*)prm)[i];
    float sv, cv;
    sincosf(0.5f * a, &sv, &cv);
    csb[i] = cv; csb[66 + i] = sv;
  }
}
__global__ void __launch_bounds__(256)
kinit(const void* s0, const void* s1, float* d0, float* d1,
      const int* __restrict__ flag, int basepl) {
  int pl = blockIdx.y + basepl;
  int f = *flag;
  const void* src = (pl ^ (f ? 0 : 1)) ? s1 : s0;
  float* dst = pl ? d1 : d0;
  unsigned p = blockIdx.x * 256 + threadIdx.x;
  unsigned q = (p ^ (p << 2)) & IDXMASK;
  dst[p] = f ? bf2f(((const unsigned short*)src)[q]) : ((const float*)src)[q];
}
__global__ void __launch_bounds__(256)
kpass(float* b0, float* b1, const float* __restrict__ csb,
      int L, int qa, unsigned ma, unsigned mb) {
  int k = L * 22 + qa;
  float ca = csb[k], sa = csb[66 + k];
  float cb = csb[k + 1], sb = csb[66 + k + 1];
  float* buf = blockIdx.y ? b1 : b0;
  unsigned t = blockIdx.x * 256 + threadIdx.x;
  unsigned j = (t & ((1u << qa) - 1u)) | ((t >> qa) << (qa + 2));
  unsigned p = j;
  if (L == 0)      { p ^= p << 2; p ^= p << 4; p ^= p << 8; p ^= p << 16; }
  else if (L == 1) { p ^= p << 1; p ^= p << 2; p ^= p << 4; p ^= p << 8; p ^= p << 16; }
  p &= IDXMASK;
  unsigned mc = ma ^ mb;
  float x0 = buf[p], x1 = buf[p ^ ma], x2 = buf[p ^ mb], x3 = buf[p ^ mc];
  float y0 = ca * x0 - sa * x1, y1 = sa * x0 + ca * x1;
  float y2 = ca * x2 - sa * x3, y3 = sa * x2 + ca * x3;
  buf[p]      = cb * y0 - sb * y2;
  buf[p ^ ma] = cb * y1 - sb * y3;
  buf[p ^ mb] = sb * y0 + cb * y2;
  buf[p ^ mc] = sb * y1 + cb * y3;
}
__global__ void __launch_bounds__(256)
kpark(const float* __restrict__ fv, unsigned short* __restrict__ park) {
  unsigned j = blockIdx.x * 256 + threadIdx.x;
  park[j] = f2bf(fv[j]);
}
__global__ void __launch_bounds__(256)
kmerge(const unsigned short* __restrict__ park, unsigned int* outw) {
  unsigned j = blockIdx.x * 256 + threadIdx.x;
  float vv = __uint_as_float(outw[j]);
  outw[j] = (unsigned)park[j] | ((unsigned)f2bf(vv) << 16);
}
static inline unsigned pmask(int q, int L) {
  unsigned r = 0;
  if (L == 0)      for (unsigned m = 1u << q; m < NSTATES; m <<= 2) r ^= m;
  else if (L == 1) for (unsigned m = 1u << q; m < NSTATES; m <<= 1) r ^= m;
  else r = 1u << q;
  return r;
}

extern "C" void kernel_launch(void* const* d_in, const int* in_sizes, int n_in,
                              void* d_out, int out_size, void* d_ws, size_t ws_size,
                              hipStream_t stream) {
  (void)out_size;
  const void* prm = d_in[0];
  const void* re  = d_in[1];
  const void* im  = d_in[2];
  if (in_sizes[0] != 66) {   // defensive size-based remap
    const void* big[2] = {nullptr, nullptr};
    int nb = 0;
    for (int i = 0; i < n_in; ++i) {
      if (in_sizes[i] == 66) prm = d_in[i];
      else if (nb < 2) big[nb++] = d_in[i];
    }
    if (nb == 2) { re = big[0]; im = big[1]; }
  }
  const size_t N = NSTATES;

  if (ws_size >= N * 8 + 1024) {
    // ---- fast path: 2 window-phase sweeps (packed bf16 W') + gather ----
    unsigned* W = (unsigned*)d_ws;
    unsigned* tmp = W + N;
    ksweep1<<<dim3(512), 512, 0, stream>>>(re, im, W, prm);
    ksweep2<<<dim3(512), 512, 0, stream>>>(W, tmp, re, prm);
    kfinal<<<dim3(4096), 256, 0, stream>>>(tmp, (unsigned*)d_out);
  } else {
    // ---- tier C (proven R6): d_out as f32 buffer; ~8.4MB ws ----
    float* F = (float*)d_out;
    unsigned short* park = (unsigned short*)d_ws;
    float* csb = (float*)((char*)d_ws + N * 2);
    int* flag = (int*)(csb + 140);
    dim3 blk(256);
    ksetup<<<1, 256, 0, stream>>>((const unsigned int*)re, prm, csb, flag);
    kinit<<<dim3(16384, 1), blk, 0, stream>>>(re, im, F, F, flag, 0);
    for (int L = 0; L < 3; ++L)
      for (int qa = 0; qa < 22; qa += 2)
        kpass<<<dim3(4096, 1), blk, 0, stream>>>(F, F, csb, L, qa,
                                                 pmask(qa, L), pmask(qa + 1, L));
    kpark<<<dim3(16384), blk, 0, stream>>>(F, park);
    kinit<<<dim3(16384, 1), blk, 0, stream>>>(re, im, F, F, flag, 1);
    for (int L = 0; L < 3; ++L)
      for (int qa = 0; qa < 22; qa += 2)
        kpass<<<dim3(4096, 1), blk, 0, stream>>>(F, F, csb, L, qa,
                                                 pmask(qa, L), pmask(qa + 1, L));
    kmerge<<<dim3(16384), blk, 0, stream>>>(park, (unsigned int*)d_out);
  }
}

// Round 20
// 62.806 us; speedup vs baseline: 2.3580x; 1.0226x over previous
//
#include <hip/hip_runtime.h>

// 22-qubit, 3-layer RY variational circuit — forward-frame, window-phase version.
// Real/imag planes evolve independently (all gates real).
//
// Forward frame: state in natural order; CNOT chains folded into masks/signs.
//   L0 q: mask e_q;  L1 q: mask e_q^e_{q+1}, sign parity(p_0..p_q);
//   L2 q: mask e_q^e_{q+2}, sign parity(p_q,p_{q-2},..);  out[l]=buf[sigma^2(l)].
//
// R20 = R19 (passing, absmax 0.0625) + two bit-identical optimizations:
//  (1) LDS address folding via GF(2) linearity of SW: SW(lb|i<<S) = SW(lb) ^
//      SW(i<<S) (disjoint bits, verified per pattern); base computed once.
//  (2) P2/Q2 write back as packed bf16 u16 halves (plane0 lo / plane1 hi) into
//      region0; pack loop reads ready u32 words (16 fewer LDS reads/thread,
//      no pack-time f2bf). Same single rounding, moved earlier. One extra
//      barrier separates cross-plane reads from u16 writes.

#define NQ 22
#define NSTATES (1u << NQ)
#define IDXMASK (NSTATES - 1u)

__device__ __forceinline__ unsigned short f2bf(float x) {
  unsigned int b = __float_as_uint(x);
  b += 0x7FFFu + ((b >> 16) & 1u);   // round-to-nearest-even
  return (unsigned short)(b >> 16);
}
__device__ __forceinline__ float bf2f(unsigned short h) {
  return __uint_as_float((unsigned int)h << 16);
}
// LDS swizzle for 13-bit local index: bank bits 0..4 ^= l5..9 ^ l10..12.
// GF(2)-linear: SW(a^b) = SW(a)^SW(b).
__device__ __forceinline__ constexpr unsigned SW(unsigned l) {
  return l ^ ((l >> 5) & 31u) ^ ((l >> 10) & 7u);
}

// Generalized RY butterfly (pair enumeration by LOWEST set bit of MR).
template <int ML, int MR, int RS, unsigned SM, int N>
__device__ __forceinline__ void rot(float (&v)[N], float c, float s, unsigned pbase) {
  int sb = __popc(pbase & SM) & 1;
  float sp = sb ? s : -s;
  constexpr int LB = MR & (-MR);
  if (ML == 0) {
#pragma unroll
    for (int i = 0; i < N; ++i)
      if (!(i & LB)) {
        const int j = i ^ MR;
        const int pi = __builtin_popcount(((unsigned)i << RS) & SM) & 1;
        const int pj = __builtin_popcount(((unsigned)j << RS) & SM) & 1;
        float a = v[i], b = v[j];
        v[i] = fmaf(pi ? -sp : sp, b, c * a);
        v[j] = fmaf(pj ? -sp : sp, a, c * b);
      }
  } else if (MR == 0) {
#pragma unroll
    for (int i = 0; i < N; ++i) {
      float o = __shfl_xor(v[i], ML, 64);
      const int pi = __builtin_popcount(((unsigned)i << RS) & SM) & 1;
      v[i] = fmaf(pi ? -sp : sp, o, c * v[i]);
    }
  } else {
#pragma unroll
    for (int i = 0; i < N; ++i)
      if (!(i & LB)) {
        const int j = i ^ MR;
        float oa = __shfl_xor(v[j], ML, 64);
        float ob = __shfl_xor(v[i], ML, 64);
        const int pi = __builtin_popcount(((unsigned)i << RS) & SM) & 1;
        const int pj = __builtin_popcount(((unsigned)j << RS) & SM) & 1;
        v[i] = fmaf(pi ? -sp : sp, oa, c * v[i]);
        v[j] = fmaf(pj ? -sp : sp, ob, c * v[j]);
      }
  }
}

// in-block setup: flag from probe words + 66 sincos pairs into LDS
__device__ __forceinline__ int blk_setup(const void* re, const void* prm,
                                         float* cs2, int tid) {
  int bad = 0;
  const unsigned* pr = (const unsigned*)re;
#pragma unroll
  for (int i = 0; i < 64; ++i) bad |= (((pr[i] >> 7) & 0xFFu) >= 0x90u);
  int f = bad ? 0 : 1;
  if (tid < 66) {
    float a = f ? bf2f(((const unsigned short*)prm)[tid])
                : ((const float*)prm)[tid];
    float sv, cv;
    sincosf(0.5f * a, &sv, &cv);
    cs2[tid] = cv; cs2[66 + tid] = sv;
  }
  __syncthreads();
  return f;
}

#define RC(k) csb[k], csb[66 + (k)]

// ---- sweep 1: masks within bits 0..12 (36 gates), 3 window phases ----
// 512 threads: waves 0-3 plane-re, 4-7 plane-im; 2 x 32KB LDS; B = p13..21.
// P0 regs=l0..4 (direct global load); P1 regs=l4..8 (+mixed L2 q3);
// P2 regs=l8..12 (+mixed L2 q7), writes packed bf16 u16 into region0.
// Store: packed u32 (re|im) to W[cb9<<13 | B<<4 | h2<<2 | e].
__global__ void __launch_bounds__(512, 4)
ksweep1(const void* re, const void* im, unsigned* __restrict__ W,
        const void* prm) {
  __shared__ float ld[2][8192];
  __shared__ float cs2[132];
  int tid = threadIdx.x;
  int f = blk_setup(re, prm, cs2, tid);
  const float* csb = cs2;

  int pl = tid >> 8;
  int htid = tid & 255;
  int lane = htid & 63, wv = htid >> 6;          // wv 0..3
  const void* src = (pl ^ (f ? 0 : 1)) ? im : re;
  float* L = ld[pl];
  unsigned B = blockIdx.x;
  unsigned tb = B << 13;
  float v[32];

  // ---- P0: window {0..4}: direct load of 32 consecutive elems ----
  unsigned lb0 = ((unsigned)lane << 5) | ((unsigned)wv << 11);
  unsigned pb0 = tb | lb0;
  if (f) {
    const unsigned short* sp = (const unsigned short*)src + tb + lb0;
#pragma unroll
    for (int j = 0; j < 4; ++j) {
      uint4 q = *reinterpret_cast<const uint4*>(sp + j * 8);
      v[j*8+0]=bf2f((unsigned short)(q.x & 0xFFFFu));
      v[j*8+1]=bf2f((unsigned short)(q.x >> 16));
      v[j*8+2]=bf2f((unsigned short)(q.y & 0xFFFFu));
      v[j*8+3]=bf2f((unsigned short)(q.y >> 16));
      v[j*8+4]=bf2f((unsigned short)(q.z & 0xFFFFu));
      v[j*8+5]=bf2f((unsigned short)(q.z >> 16));
      v[j*8+6]=bf2f((unsigned short)(q.w & 0xFFFFu));
      v[j*8+7]=bf2f((unsigned short)(q.w >> 16));
    }
  } else {
    const float* sp = (const float*)src + tb + lb0;
#pragma unroll
    for (int j = 0; j < 8; ++j) {
      float4 t = *reinterpret_cast<const float4*>(sp + j * 4);
      v[j*4+0]=t.x; v[j*4+1]=t.y; v[j*4+2]=t.z; v[j*4+3]=t.w;
    }
  }
  rot<0, 1, 0, 0x1u>(v, RC(0), pb0);
  rot<0, 2, 0, 0x2u>(v, RC(1), pb0);
  rot<0, 4, 0, 0x4u>(v, RC(2), pb0);
  rot<0, 8, 0, 0x8u>(v, RC(3), pb0);
  rot<0, 16, 0, 0x10u>(v, RC(4), pb0);
  rot<0, 3, 0, 0x1u>(v, RC(22), pb0);
  rot<0, 6, 0, 0x3u>(v, RC(23), pb0);
  rot<0, 12, 0, 0x7u>(v, RC(24), pb0);
  rot<0, 24, 0, 0xFu>(v, RC(25), pb0);
  rot<0, 5, 0, 0x1u>(v, RC(44), pb0);
  rot<0, 10, 0, 0x2u>(v, RC(45), pb0);
  rot<0, 20, 0, 0x5u>(v, RC(46), pb0);
  {
    unsigned b0s = SW(lb0);
#pragma unroll
    for (int i = 0; i < 32; ++i) L[b0s ^ (unsigned)i] = v[i];
  }
  __syncthreads();

  // ---- P1: window {4..8}: L0 q5..8; L1 q4..7; L2 q3(mixed),q4..6 ----
  unsigned lb1 = ((unsigned)lane & 15u) | ((((unsigned)lane >> 4) & 3u) << 9) |
                 ((unsigned)wv << 11);
  unsigned pb1 = tb | lb1;
  {
    unsigned b1s = SW(lb1);
#pragma unroll
    for (int i = 0; i < 32; ++i) v[i] = L[b1s ^ SW((unsigned)i << 4)];
    rot<0, 2, 4, 0x20u>(v, RC(5), pb1);
    rot<0, 4, 4, 0x40u>(v, RC(6), pb1);
    rot<0, 8, 4, 0x80u>(v, RC(7), pb1);
    rot<0, 16, 4, 0x100u>(v, RC(8), pb1);
    rot<0, 3, 4, 0x1Fu>(v, RC(26), pb1);
    rot<0, 6, 4, 0x3Fu>(v, RC(27), pb1);
    rot<0, 12, 4, 0x7Fu>(v, RC(28), pb1);
    rot<0, 24, 4, 0xFFu>(v, RC(29), pb1);
    rot<8, 2, 4, 0xAu>(v, RC(47), pb1);     // L2 q3: mask (3,5), bit3=lane3
    rot<0, 5, 4, 0x15u>(v, RC(48), pb1);
    rot<0, 10, 4, 0x2Au>(v, RC(49), pb1);
    rot<0, 20, 4, 0x55u>(v, RC(50), pb1);
#pragma unroll
    for (int i = 0; i < 32; ++i) L[b1s ^ SW((unsigned)i << 4)] = v[i];
  }
  __syncthreads();

  // ---- P2: window {8..12}: L0 q9..12; L1 q8..11; L2 q7(mixed),q8..10 ----
  unsigned lb2 = ((unsigned)lane & 31u) | ((unsigned)wv << 5) |
                 ((((unsigned)lane >> 5) & 1u) << 7);
  unsigned pb2 = tb | lb2;
  unsigned b2s = SW(lb2);
#pragma unroll
  for (int i = 0; i < 32; ++i) v[i] = L[b2s ^ SW((unsigned)i << 8)];
  rot<0, 2, 8, 0x200u>(v, RC(9), pb2);
  rot<0, 4, 8, 0x400u>(v, RC(10), pb2);
  rot<0, 8, 8, 0x800u>(v, RC(11), pb2);
  rot<0, 16, 8, 0x1000u>(v, RC(12), pb2);
  rot<0, 3, 8, 0x1FFu>(v, RC(30), pb2);
  rot<0, 6, 8, 0x3FFu>(v, RC(31), pb2);
  rot<0, 12, 8, 0x7FFu>(v, RC(32), pb2);
  rot<0, 24, 8, 0xFFFu>(v, RC(33), pb2);
  rot<32, 2, 8, 0xAAu>(v, RC(51), pb2);   // L2 q7: mask (7,9), bit7=lane5
  rot<0, 5, 8, 0x155u>(v, RC(52), pb2);
  rot<0, 10, 8, 0x2AAu>(v, RC(53), pb2);
  rot<0, 20, 8, 0x555u>(v, RC(54), pb2);
  __syncthreads();   // all P2 reads done before cross-plane u16 writes
  {
    unsigned short* H = (unsigned short*)&ld[0][0];
#pragma unroll
    for (int i = 0; i < 32; ++i)
      H[((b2s ^ SW((unsigned)i << 8)) << 1) | (unsigned)pl] = f2bf(v[i]);
  }
  __syncthreads();

  // ---- packed store from region0 u32 words: W[cb9<<13|B<<4|h2<<2|e] ----
  {
    const unsigned* U = (const unsigned*)&ld[0][0];
#pragma unroll
    for (int k = 0; k < 4; ++k) {
      unsigned t = (unsigned)k * 512 + tid;   // 0..2047 chunk id
      unsigned cb9 = t >> 2, h2 = t & 3;
      unsigned bp = SW((cb9 << 2) | (h2 << 11));
      uint4 o;
      o.x = U[bp];
      o.y = U[bp ^ 1u];
      o.z = U[bp ^ 2u];
      o.w = U[bp ^ 3u];
      *reinterpret_cast<uint4*>(W + ((((cb9 << 11) | (B << 2) | h2) << 2))) = o;
    }
  }
}

// ---- sweep 2: masks within bits 11..21 (30 gates), 3 window phases ----
// 512 threads (waves 0-3 re / 4-7 im), 2x32KB LDS, cb = p2..10.
// Stage: CONTIGUOUS 32KB u32 slab W + cb<<13 (in-slab offset o == local l).
__global__ void __launch_bounds__(512, 4)
ksweep2(const unsigned* __restrict__ W, unsigned* __restrict__ tmp,
        const void* re, const void* prm) {
  __shared__ float ld[2][8192];
  __shared__ float cs2[132];
  int tid = threadIdx.x;
  (void)blk_setup(re, prm, cs2, tid);
  const float* csb = cs2;
  unsigned cb = blockIdx.x;             // p2..10

#pragma unroll
  for (int k = 0; k < 4; ++k) {
    unsigned C = (unsigned)k * 512 + tid;   // 0..2047 chunks of 4 u32
    uint4 q = *reinterpret_cast<const uint4*>(W + (cb << 13) + C * 4);
    unsigned so = SW(C * 4);
    ld[0][so]      = bf2f((unsigned short)(q.x & 0xFFFFu));
    ld[1][so]      = bf2f((unsigned short)(q.x >> 16));
    ld[0][so ^ 1u] = bf2f((unsigned short)(q.y & 0xFFFFu));
    ld[1][so ^ 1u] = bf2f((unsigned short)(q.y >> 16));
    ld[0][so ^ 2u] = bf2f((unsigned short)(q.z & 0xFFFFu));
    ld[1][so ^ 2u] = bf2f((unsigned short)(q.z >> 16));
    ld[0][so ^ 3u] = bf2f((unsigned short)(q.w & 0xFFFFu));
    ld[1][so ^ 3u] = bf2f((unsigned short)(q.w >> 16));
  }
  __syncthreads();

  int lane = tid & 63;
  int wq = (tid >> 6) & 3;
  int pl = tid >> 8;                    // plane
  float* L = ld[pl];
  float v[32];

  // ---- Q0: phys {11..15}: L0 q13..15; L1 q12..14; L2 q11..13 ----
  unsigned lbQ0 = ((unsigned)lane & 3u) | ((((unsigned)lane >> 2) & 15u) << 7) |
                  ((unsigned)wq << 11);
  unsigned pb0 = ((unsigned)lane & 3u) | (cb << 2) |
                 ((((unsigned)lane >> 2) & 15u) << 16) | ((unsigned)wq << 20);
  {
    unsigned bq0 = SW(lbQ0);
#pragma unroll
    for (int i = 0; i < 32; ++i) v[i] = L[bq0 ^ SW((unsigned)i << 2)];
    rot<0, 4, 11, (1u << 13)>(v, RC(13), pb0);
    rot<0, 8, 11, (1u << 14)>(v, RC(14), pb0);
    rot<0, 16, 11, (1u << 15)>(v, RC(15), pb0);
    rot<0, 6, 11, 0x1FFFu>(v, RC(34), pb0);
    rot<0, 12, 11, 0x3FFFu>(v, RC(35), pb0);
    rot<0, 24, 11, 0x7FFFu>(v, RC(36), pb0);
    rot<0, 5, 11, 0xAAAu>(v, RC(55), pb0);
    rot<0, 10, 11, 0x1555u>(v, RC(56), pb0);
    rot<0, 20, 11, 0x2AAAu>(v, RC(57), pb0);
#pragma unroll
    for (int i = 0; i < 32; ++i) L[bq0 ^ SW((unsigned)i << 2)] = v[i];
  }
  __syncthreads();

  // ---- Q1: phys {14..18}: L0 q16..18; L1 q15..17; L2 q14..16 ----
  unsigned lbQ1 = ((unsigned)lane & 31u) | ((((unsigned)lane >> 5) & 1u) << 10) |
                  ((unsigned)wq << 11);
  unsigned pb1 = ((unsigned)lane & 3u) | (cb << 2) |
                 ((((unsigned)lane >> 2) & 7u) << 11) |
                 ((((unsigned)lane >> 5) & 1u) << 19) | ((unsigned)wq << 20);
  {
    unsigned bq1 = SW(lbQ1);
#pragma unroll
    for (int i = 0; i < 32; ++i) v[i] = L[bq1 ^ SW((unsigned)i << 5)];
    rot<0, 4, 14, (1u << 16)>(v, RC(16), pb1);
    rot<0, 8, 14, (1u << 17)>(v, RC(17), pb1);
    rot<0, 16, 14, (1u << 18)>(v, RC(18), pb1);
    rot<0, 6, 14, 0xFFFFu>(v, RC(37), pb1);
    rot<0, 12, 14, 0x1FFFFu>(v, RC(38), pb1);
    rot<0, 24, 14, 0x3FFFFu>(v, RC(39), pb1);
    rot<0, 5, 14, 0x5555u>(v, RC(58), pb1);
    rot<0, 10, 14, 0xAAAAu>(v, RC(59), pb1);
    rot<0, 20, 14, 0x15555u>(v, RC(60), pb1);
#pragma unroll
    for (int i = 0; i < 32; ++i) L[bq1 ^ SW((unsigned)i << 5)] = v[i];
  }
  __syncthreads();

  // ---- Q2: phys {17..21}: L0 q19..21; L1 q18..21; L2 q17..21 ----
  unsigned lbQ2 = ((unsigned)lane & 63u) | ((unsigned)wq << 6);
  unsigned pb2 = ((unsigned)lane & 3u) | (cb << 2) |
                 ((((unsigned)lane >> 2) & 15u) << 11) | ((unsigned)wq << 15);
  unsigned bq2 = SW(lbQ2);
#pragma unroll
  for (int i = 0; i < 32; ++i) v[i] = L[bq2 ^ SW((unsigned)i << 8)];
  rot<0, 4, 17, (1u << 19)>(v, RC(19), pb2);
  rot<0, 8, 17, (1u << 20)>(v, RC(20), pb2);
  rot<0, 16, 17, (1u << 21)>(v, RC(21), pb2);
  rot<0, 6, 17, 0x7FFFFu>(v, RC(40), pb2);
  rot<0, 12, 17, 0xFFFFFu>(v, RC(41), pb2);
  rot<0, 24, 17, 0x1FFFFFu>(v, RC(42), pb2);
  rot<0, 16, 17, 0x3FFFFFu>(v, RC(43), pb2);
  rot<0, 5, 17, 0x2AAAAu>(v, RC(61), pb2);
  rot<0, 10, 17, 0x55555u>(v, RC(62), pb2);
  rot<0, 20, 17, 0xAAAAAu>(v, RC(63), pb2);
  rot<0, 8, 17, 0x155555u>(v, RC(64), pb2);
  rot<0, 16, 17, 0x2AAAAAu>(v, RC(65), pb2);
  __syncthreads();   // all Q2 reads done before cross-plane u16 writes
  {
    unsigned short* H = (unsigned short*)&ld[0][0];
#pragma unroll
    for (int i = 0; i < 32; ++i)
      H[((bq2 ^ SW((unsigned)i << 8)) << 1) | (unsigned)pl] = f2bf(v[i]);
  }
  __syncthreads();

  // pack region0 u32 words -> p-linear tmp: p = e | cb<<2 | hh<<11
  {
    const unsigned* U = (const unsigned*)&ld[0][0];
#pragma unroll
    for (int k = 0; k < 4; ++k) {
      unsigned Q = (unsigned)k * 512 + tid;   // hh
      unsigned se = SW(Q << 2);
      uint4 o;
      o.x = U[se];
      o.y = U[se ^ 1u];
      o.z = U[se ^ 2u];
      o.w = U[se ^ 3u];
      *reinterpret_cast<uint4*>(tmp + (((size_t)Q << 11) | (cb << 2))) = o;
    }
  }
}

// ---- final gather: out[l] = tmp[sigma^2(l)] (R13-proven) ----
__global__ void __launch_bounds__(256)
kfinal(const unsigned* __restrict__ tmp, unsigned* __restrict__ out32) {
  unsigned T = blockIdx.x * 256 + threadIdx.x;   // quad id [0, 2^20)
  unsigned lb = T << 2;
  unsigned s = (lb ^ (lb << 2)) & IDXMASK;       // %4 == 0
  const uint4* w = reinterpret_cast<const uint4*>(tmp + (s & ~15u));
  uint4 a = w[0], b = w[1], c = w[2], d = w[3];
  uint4 o;
  switch ((s >> 2) & 3u) {
    case 0: o = make_uint4(a.x, b.y, c.z, d.w); break;   // 0,5,10,15
    case 1: o = make_uint4(b.x, a.y, d.z, c.w); break;   // 4,1,14,11
    case 2: o = make_uint4(c.x, d.y, a.z, b.w); break;   // 8,13,2,7
    default: o = make_uint4(d.x, c.y, b.z, a.w); break;  // 12,9,6,3
  }
  *reinterpret_cast<uint4*>(out32 + lb) = o;
}

// ---------------- proven tier-C fallback (R6) ----------------
__global__ void ksetup(const unsigned int* __restrict__ probe,
                       const void* __restrict__ prm,
                       float* __restrict__ csb, int* __restrict__ flagp) {
  __shared__ int anybad;
  if (threadIdx.x == 0) anybad = 0;
  __syncthreads();
  int bad = 0;
  for (int i = threadIdx.x; i < 4096; i += 256) {
    unsigned e = (probe[i] >> 7) & 0xFFu;
    bad |= (e >= 0x90u);
  }
  if (bad) anybad = 1;
  __syncthreads();
  int f = anybad ? 0 : 1;
  if (threadIdx.x == 0) *flagp = f;
  int i = threadIdx.x;
  if (i < 66) {
    float a = f ? bf2f(((const unsigned short*)prm)[i]) : ((const float*)prm)[i];
    float sv, cv;
    sincosf(0.5f * a, &sv, &cv);
    csb[i] = cv; csb[66 + i] = sv;
  }
}
__global__ void __launch_bounds__(256)
kinit(const void* s0, const void* s1, float* d0, float* d1,
      const int* __restrict__ flag, int basepl) {
  int pl = blockIdx.y + basepl;
  int f = *flag;
  const void* src = (pl ^ (f ? 0 : 1)) ? s1 : s0;
  float* dst = pl ? d1 : d0;
  unsigned p = blockIdx.x * 256 + threadIdx.x;
  unsigned q = (p ^ (p << 2)) & IDXMASK;
  dst[p] = f ? bf2f(((const unsigned short*)src)[q]) : ((const float*)src)[q];
}
__global__ void __launch_bounds__(256)
kpass(float* b0, float* b1, const float* __restrict__ csb,
      int L, int qa, unsigned ma, unsigned mb) {
  int k = L * 22 + qa;
  float ca = csb[k], sa = csb[66 + k];
  float cb = csb[k + 1], sb = csb[66 + k + 1];
  float* buf = blockIdx.y ? b1 : b0;
  unsigned t = blockIdx.x * 256 + threadIdx.x;
  unsigned j = (t & ((1u << qa) - 1u)) | ((t >> qa) << (qa + 2));
  unsigned p = j;
  if (L == 0)      { p ^= p << 2; p ^= p << 4; p ^= p << 8; p ^= p << 16; }
  else if (L == 1) { p ^= p << 1; p ^= p << 2; p ^= p << 4; p ^= p << 8; p ^= p << 16; }
  p &= IDXMASK;
  unsigned mc = ma ^ mb;
  float x0 = buf[p], x1 = buf[p ^ ma], x2 = buf[p ^ mb], x3 = buf[p ^ mc];
  float y0 = ca * x0 - sa * x1, y1 = sa * x0 + ca * x1;
  float y2 = ca * x2 - sa * x3, y3 = sa * x2 + ca * x3;
  buf[p]      = cb * y0 - sb * y2;
  buf[p ^ ma] = cb * y1 - sb * y3;
  buf[p ^ mb] = sb * y0 + cb * y2;
  buf[p ^ mc] = sb * y1 + cb * y3;
}
__global__ void __launch_bounds__(256)
kpark(const float* __restrict__ fv, unsigned short* __restrict__ park) {
  unsigned j = blockIdx.x * 256 + threadIdx.x;
  park[j] = f2bf(fv[j]);
}
__global__ void __launch_bounds__(256)
kmerge(const unsigned short* __restrict__ park, unsigned int* outw) {
  unsigned j = blockIdx.x * 256 + threadIdx.x;
  float vv = __uint_as_float(outw[j]);
  outw[j] = (unsigned)park[j] | ((unsigned)f2bf(vv) << 16);
}
static inline unsigned pmask(int q, int L) {
  unsigned r = 0;
  if (L == 0)      for (unsigned m = 1u << q; m < NSTATES; m <<= 2) r ^= m;
  else if (L == 1) for (unsigned m = 1u << q; m < NSTATES; m <<= 1) r ^= m;
  else r = 1u << q;
  return r;
}

extern "C" void kernel_launch(void* const* d_in, const int* in_sizes, int n_in,
                              void* d_out, int out_size, void* d_ws, size_t ws_size,
                              hipStream_t stream) {
  (void)out_size;
  const void* prm = d_in[0];
  const void* re  = d_in[1];
  const void* im  = d_in[2];
  if (in_sizes[0] != 66) {   // defensive size-based remap
    const void* big[2] = {nullptr, nullptr};
    int nb = 0;
    for (int i = 0; i < n_in; ++i) {
      if (in_sizes[i] == 66) prm = d_in[i];
      else if (nb < 2) big[nb++] = d_in[i];
    }
    if (nb == 2) { re = big[0]; im = big[1]; }
  }
  const size_t N = NSTATES;

  if (ws_size >= N * 8 + 1024) {
    // ---- fast path: 2 window-phase sweeps (packed bf16 W') + gather ----
    unsigned* W = (unsigned*)d_ws;
    unsigned* tmp = W + N;
    ksweep1<<<dim3(512), 512, 0, stream>>>(re, im, W, prm);
    ksweep2<<<dim3(512), 512, 0, stream>>>(W, tmp, re, prm);
    kfinal<<<dim3(4096), 256, 0, stream>>>(tmp, (unsigned*)d_out);
  } else {
    // ---- tier C (proven R6): d_out as f32 buffer; ~8.4MB ws ----
    float* F = (float*)d_out;
    unsigned short* park = (unsigned short*)d_ws;
    float* csb = (float*)((char*)d_ws + N * 2);
    int* flag = (int*)(csb + 140);
    dim3 blk(256);
    ksetup<<<1, 256, 0, stream>>>((const unsigned int*)re, prm, csb, flag);
    kinit<<<dim3(16384, 1), blk, 0, stream>>>(re, im, F, F, flag, 0);
    for (int L = 0; L < 3; ++L)
      for (int qa = 0; qa < 22; qa += 2)
        kpass<<<dim3(4096, 1), blk, 0, stream>>>(F, F, csb, L, qa,
                                                 pmask(qa, L), pmask(qa + 1, L));
    kpark<<<dim3(16384), blk, 0, stream>>>(F, park);
    kinit<<<dim3(16384, 1), blk, 0, stream>>>(re, im, F, F, flag, 1);
    for (int L = 0; L < 3; ++L)
      for (int qa = 0; qa < 22; qa += 2)
        kpass<<<dim3(4096, 1), blk, 0, stream>>>(F, F, csb, L, qa,
                                                 pmask(qa, L), pmask(qa + 1, L));
    kmerge<<<dim3(16384), blk, 0, stream>>>(park, (unsigned int*)d_out);
  }
}